// Round 1
// baseline (1511.256 us; speedup 1.0000x reference)
//
#include <hip/hip_runtime.h>

typedef __bf16 bf16_t;
typedef __bf16 bf16x8 __attribute__((ext_vector_type(8)));
typedef __bf16 bf16x4 __attribute__((ext_vector_type(4)));
typedef float  f32x4  __attribute__((ext_vector_type(4)));

#define NB   2
#define NS   2048
#define ND   4096
#define NH   32
#define NKVH 8
#define NHD  128

__device__ __forceinline__ void gl_lds16(const bf16_t* g, bf16_t* l) {
  __builtin_amdgcn_global_load_lds(
      (const __attribute__((address_space(1))) void*)g,
      (__attribute__((address_space(3))) void*)l, 16, 0, 0);
}

// ---------------- convert x fp32 -> bf16 ----------------
__global__ void convert_f32_bf16(const float* __restrict__ in, bf16_t* __restrict__ out, int n4) {
  int i = blockIdx.x * 256 + threadIdx.x;
  if (i < n4) {
    f32x4 v = *(const f32x4*)&in[(size_t)i * 4];
    bf16x4 o;
    #pragma unroll
    for (int j = 0; j < 4; ++j) o[j] = (bf16_t)v[j];
    *(bf16x4*)&out[(size_t)i * 4] = o;
  }
}

// ------------- transpose-convert W[4096][Nin] fp32 -> Wt[Nin][4096] bf16 -------------
__global__ void transpose_convert(const float* __restrict__ in, bf16_t* __restrict__ out, int Nin) {
  __shared__ float t[32][33];
  int tx = threadIdx.x & 31, ty = threadIdx.x >> 5;
  int n0 = blockIdx.x * 32, k0 = blockIdx.y * 32;
  #pragma unroll
  for (int i = 0; i < 4; ++i)
    t[ty + i * 8][tx] = in[(size_t)(k0 + ty + i * 8) * Nin + n0 + tx];
  __syncthreads();
  #pragma unroll
  for (int i = 0; i < 4; ++i)
    out[(size_t)(n0 + ty + i * 8) * 4096 + k0 + tx] = (bf16_t)t[tx][ty + i * 8];
}

// ---------------- GEMM: C[M][N] = A[M][K] * Bt[N][K]^T  (bf16 in, fp32 acc) ----------------
template <int F32OUT>
__global__ __launch_bounds__(256) void gemm_bt(const bf16_t* __restrict__ A,
                                               const bf16_t* __restrict__ Bt,
                                               void* __restrict__ Cv, int M, int N, int K) {
  __shared__ __align__(16) bf16_t As[128 * 32];
  __shared__ __align__(16) bf16_t Bs[128 * 32];
  const int tid = threadIdx.x;
  const int lane = tid & 63, wid = tid >> 6;
  const int l15 = lane & 15, l4 = lane >> 4;
  const int wr = wid >> 1, wc = wid & 1;
  const int row0 = blockIdx.x * 128, col0 = blockIdx.y * 128;

  f32x4 acc[4][4];
  #pragma unroll
  for (int m = 0; m < 4; ++m)
    #pragma unroll
    for (int n = 0; n < 4; ++n)
      #pragma unroll
      for (int j = 0; j < 4; ++j) acc[m][n][j] = 0.f;

  const bf16_t* Ab = A + (size_t)row0 * K;
  const bf16_t* Bb = Bt + (size_t)col0 * K;

  for (int k0 = 0; k0 < K; k0 += 32) {
    #pragma unroll
    for (int i = 0; i < 2; ++i) {
      int ci = i * 256 + tid;  // 512 chunks of 16B per 128x32 tile
      gl_lds16(Ab + (size_t)(ci >> 2) * K + k0 + (ci & 3) * 8, &As[ci * 8]);
      gl_lds16(Bb + (size_t)(ci >> 2) * K + k0 + (ci & 3) * 8, &Bs[ci * 8]);
    }
    __syncthreads();
    bf16x8 af[4], bfr[4];
    #pragma unroll
    for (int m = 0; m < 4; ++m)
      af[m] = *(const bf16x8*)&As[(wr * 64 + m * 16 + l15) * 32 + l4 * 8];
    #pragma unroll
    for (int n = 0; n < 4; ++n)
      bfr[n] = *(const bf16x8*)&Bs[(wc * 64 + n * 16 + l15) * 32 + l4 * 8];
    #pragma unroll
    for (int m = 0; m < 4; ++m)
      #pragma unroll
      for (int n = 0; n < 4; ++n)
        acc[m][n] = __builtin_amdgcn_mfma_f32_16x16x32_bf16(af[m], bfr[n], acc[m][n], 0, 0, 0);
    __syncthreads();
  }

  #pragma unroll
  for (int m = 0; m < 4; ++m)
    #pragma unroll
    for (int n = 0; n < 4; ++n)
      #pragma unroll
      for (int r = 0; r < 4; ++r) {
        size_t row = row0 + wr * 64 + m * 16 + l4 * 4 + r;
        size_t col = col0 + wc * 64 + n * 16 + l15;
        if (F32OUT) ((float*)Cv)[row * N + col] = acc[m][n][r];
        else ((bf16_t*)Cv)[row * N + col] = (bf16_t)acc[m][n][r];
      }
}

// ---------------- RoPE on Q and K, reshape to [b][h][s][hd] ----------------
// qkv: [4096][6144] bf16; head-slot hs<32 -> Q head, 32..39 -> K head (col = hs*128 works for both)
__global__ void rope_qk(const bf16_t* __restrict__ qkv, const float* __restrict__ cosT,
                        const float* __restrict__ sinT, bf16_t* __restrict__ Q,
                        bf16_t* __restrict__ Kout) {
  int it = blockIdx.x * 256 + threadIdx.x;  // 4096 * 40 * 16
  int chunk = it & 15;
  int hs = (it >> 4) % 40;
  int m = (it >> 4) / 40;  // b*2048 + s
  int b = m >> 11, srow = m & 2047;

  bf16x8 v = *(const bf16x8*)&qkv[(size_t)m * 6144 + hs * 128 + chunk * 8];
  f32x4 c4 = *(const f32x4*)&cosT[(size_t)srow * 64 + chunk * 4];
  f32x4 s4 = *(const f32x4*)&sinT[(size_t)srow * 64 + chunk * 4];
  bf16x8 o;
  #pragma unroll
  for (int j = 0; j < 4; ++j) {
    float t1 = (float)v[2 * j], t2 = (float)v[2 * j + 1];
    o[2 * j]     = (bf16_t)(t1 * c4[j] - t2 * s4[j]);
    o[2 * j + 1] = (bf16_t)(t1 * s4[j] + t2 * c4[j]);
  }
  bf16_t* dst;
  if (hs < 32) dst = Q + (((size_t)(b * 32 + hs)) * 2048 + srow) * 128 + chunk * 8;
  else         dst = Kout + (((size_t)(b * 8 + (hs - 32))) * 2048 + srow) * 128 + chunk * 8;
  *(bf16x8*)dst = o;
}

// ---------------- transpose V section of qkv -> Vt[b*8+kv][128][2048] ----------------
__global__ void transpose_v(const bf16_t* __restrict__ qkv, bf16_t* __restrict__ Vt) {
  __shared__ bf16_t t[32][33];
  int tx = threadIdx.x & 31, ty = threadIdx.x >> 5;
  int s0 = blockIdx.x * 32, d0 = blockIdx.y * 32, g = blockIdx.z;  // g = b*8+kv
  int b = g >> 3, kv = g & 7;
  const bf16_t* src = qkv + (size_t)(b * 2048) * 6144 + 5120 + kv * 128;
  #pragma unroll
  for (int i = 0; i < 4; ++i)
    t[ty + i * 8][tx] = src[(size_t)(s0 + ty + i * 8) * 6144 + d0 + tx];
  __syncthreads();
  bf16_t* dst = Vt + (size_t)g * 128 * 2048;
  #pragma unroll
  for (int i = 0; i < 4; ++i)
    dst[(size_t)(d0 + ty + i * 8) * 2048 + s0 + tx] = t[tx][ty + i * 8];
}

// ---------------- causal flash attention ----------------
// Q:[b][h][2048][128], K:[b][kvh][2048][128], Vt:[b][kvh][128][2048] -> O:[m][h*128+d] bf16
__global__ __launch_bounds__(256) void attn_kernel(const bf16_t* __restrict__ Q,
                                                   const bf16_t* __restrict__ Kc,
                                                   const bf16_t* __restrict__ Vt,
                                                   bf16_t* __restrict__ Oout) {
  __shared__ __align__(16) bf16_t Pl[4][16 * 32];
  const int tid = threadIdx.x, wid = tid >> 6, lane = tid & 63;
  const int l15 = lane & 15, l4 = lane >> 4;
  const int bh = blockIdx.y;
  const int b = bh >> 5, h = bh & 31, kv = h >> 2;
  const int q0 = blockIdx.x * 64 + wid * 16;  // this wave's q-row block

  const bf16_t* Qp = Q + ((size_t)bh * 2048 + q0) * 128;
  const bf16_t* Kp = Kc + ((size_t)(b * 8 + kv) * 2048) * 128;
  const bf16_t* Vp = Vt + ((size_t)(b * 8 + kv) * 128) * 2048;

  bf16x8 qf[4];
  #pragma unroll
  for (int c = 0; c < 4; ++c)
    qf[c] = *(const bf16x8*)&Qp[(size_t)l15 * 128 + c * 32 + l4 * 8];

  f32x4 o_acc[8];
  #pragma unroll
  for (int nc = 0; nc < 8; ++nc)
    #pragma unroll
    for (int j = 0; j < 4; ++j) o_acc[nc][j] = 0.f;
  float mrow[4], lrow[4];
  #pragma unroll
  for (int r = 0; r < 4; ++r) { mrow[r] = -1e30f; lrow[r] = 0.f; }

  const float scale = 0.08838834764831845f;  // 1/sqrt(128)
  const int kend = q0 + 16;

  for (int k0 = 0; k0 < kend; k0 += 32) {
    f32x4 s_acc[2];
    #pragma unroll
    for (int kc = 0; kc < 2; ++kc)
      #pragma unroll
      for (int j = 0; j < 4; ++j) s_acc[kc][j] = 0.f;
    #pragma unroll
    for (int kc = 0; kc < 2; ++kc)
      #pragma unroll
      for (int c = 0; c < 4; ++c) {
        bf16x8 kf = *(const bf16x8*)&Kp[(size_t)(k0 + kc * 16 + l15) * 128 + c * 32 + l4 * 8];
        s_acc[kc] = __builtin_amdgcn_mfma_f32_16x16x32_bf16(qf[c], kf, s_acc[kc], 0, 0, 0);
      }
    // scale + causal mask
    float p[2][4];
    #pragma unroll
    for (int kc = 0; kc < 2; ++kc)
      #pragma unroll
      for (int r = 0; r < 4; ++r) {
        float s = s_acc[kc][r] * scale;
        int key = k0 + kc * 16 + l15;
        int qrow = q0 + l4 * 4 + r;
        p[kc][r] = (key > qrow) ? -1e30f : s;
      }
    // row max across the 16 lanes holding this row's keys
    float mx[4];
    #pragma unroll
    for (int r = 0; r < 4; ++r) mx[r] = fmaxf(p[0][r], p[1][r]);
    #pragma unroll
    for (int off = 1; off < 16; off <<= 1)
      #pragma unroll
      for (int r = 0; r < 4; ++r) mx[r] = fmaxf(mx[r], __shfl_xor(mx[r], off));
    float sc[4], rs[4];
    #pragma unroll
    for (int r = 0; r < 4; ++r) {
      float mn = fmaxf(mrow[r], mx[r]);
      sc[r] = __expf(mrow[r] - mn);
      mrow[r] = mn;
      rs[r] = 0.f;
    }
    #pragma unroll
    for (int kc = 0; kc < 2; ++kc)
      #pragma unroll
      for (int r = 0; r < 4; ++r) {
        p[kc][r] = __expf(p[kc][r] - mrow[r]);
        rs[r] += p[kc][r];
      }
    #pragma unroll
    for (int off = 1; off < 16; off <<= 1)
      #pragma unroll
      for (int r = 0; r < 4; ++r) rs[r] += __shfl_xor(rs[r], off);
    #pragma unroll
    for (int r = 0; r < 4; ++r) lrow[r] = lrow[r] * sc[r] + rs[r];
    #pragma unroll
    for (int nc = 0; nc < 8; ++nc)
      #pragma unroll
      for (int r = 0; r < 4; ++r) o_acc[nc][r] *= sc[r];
    // P -> LDS (bf16), re-read as A-fragment
    bf16_t* Pw = &Pl[wid][0];
    #pragma unroll
    for (int kc = 0; kc < 2; ++kc)
      #pragma unroll
      for (int r = 0; r < 4; ++r)
        Pw[(l4 * 4 + r) * 32 + kc * 16 + l15] = (bf16_t)p[kc][r];
    bf16x8 pf = *(const bf16x8*)&Pw[l15 * 32 + l4 * 8];
    #pragma unroll
    for (int nc = 0; nc < 8; ++nc) {
      bf16x8 vf = *(const bf16x8*)&Vp[(size_t)(nc * 16 + l15) * 2048 + k0 + l4 * 8];
      o_acc[nc] = __builtin_amdgcn_mfma_f32_16x16x32_bf16(pf, vf, o_acc[nc], 0, 0, 0);
    }
  }

  float inv[4];
  #pragma unroll
  for (int r = 0; r < 4; ++r) inv[r] = 1.0f / lrow[r];
  bf16_t* Op = Oout + ((size_t)(b * 2048 + q0)) * 4096 + (size_t)h * 128;
  #pragma unroll
  for (int nc = 0; nc < 8; ++nc)
    #pragma unroll
    for (int r = 0; r < 4; ++r)
      Op[(size_t)(l4 * 4 + r) * 4096 + nc * 16 + l15] = (bf16_t)(o_acc[nc][r] * inv[r]);
}

extern "C" void kernel_launch(void* const* d_in, const int* in_sizes, int n_in,
                              void* d_out, int out_size, void* d_ws, size_t ws_size,
                              hipStream_t stream) {
  const float* x    = (const float*)d_in[0];
  const float* cosT = (const float*)d_in[1];
  const float* sinT = (const float*)d_in[2];
  const float* wq   = (const float*)d_in[3];
  const float* wk   = (const float*)d_in[4];
  const float* wv   = (const float*)d_in[5];
  const float* wo   = (const float*)d_in[6];
  float* out = (float*)d_out;
  char* ws = (char*)d_ws;

  // workspace layout (151 MB), with time-sliced aliases:
  bf16_t* wqkvT = (bf16_t*)(ws + 0);           // 6144*4096*2 = 50,331,648
  bf16_t* woT   = wqkvT;                       // reused after QKV GEMM
  bf16_t* xb    = (bf16_t*)(ws + 50331648);    // 4096*4096*2 = 33,554,432
  bf16_t* Qb    = xb;                          // reused after QKV GEMM
  bf16_t* qkv   = (bf16_t*)(ws + 83886080);    // 4096*6144*2 = 50,331,648
  bf16_t* attn_out = qkv;                      // reused after rope/transpose_v
  bf16_t* Kb    = (bf16_t*)(ws + 134217728);   // 2*8*2048*128*2 = 8,388,608
  bf16_t* Vt    = (bf16_t*)(ws + 142606336);   // 8,388,608
  // total: 150,994,944 bytes

  convert_f32_bf16<<<16384, 256, 0, stream>>>(x, xb, 4194304);
  transpose_convert<<<dim3(128, 128), 256, 0, stream>>>(wq, wqkvT, 4096);
  transpose_convert<<<dim3(32, 128), 256, 0, stream>>>(wk, wqkvT + (size_t)4096 * 4096, 1024);
  transpose_convert<<<dim3(32, 128), 256, 0, stream>>>(wv, wqkvT + (size_t)5120 * 4096, 1024);

  gemm_bt<0><<<dim3(32, 48), 256, 0, stream>>>(xb, wqkvT, qkv, 4096, 6144, 4096);

  transpose_convert<<<dim3(128, 128), 256, 0, stream>>>(wo, woT, 4096);  // wqkvT now dead
  rope_qk<<<10240, 256, 0, stream>>>(qkv, cosT, sinT, Qb, Kb);           // xb now dead
  transpose_v<<<dim3(64, 4, 16), 256, 0, stream>>>(qkv, Vt);

  attn_kernel<<<dim3(32, 64), 256, 0, stream>>>(Qb, Kb, Vt, attn_out);   // qkv now dead

  gemm_bt<1><<<dim3(32, 32), 256, 0, stream>>>(attn_out, woT, out, 4096, 4096, 4096);
}

// Round 2
// 1126.963 us; speedup vs baseline: 1.3410x; 1.3410x over previous
//
#include <hip/hip_runtime.h>

typedef __bf16 bf16_t;
typedef __bf16 bf16x8 __attribute__((ext_vector_type(8)));
typedef __bf16 bf16x4 __attribute__((ext_vector_type(4)));
typedef float  f32x4  __attribute__((ext_vector_type(4)));

#define NB   2
#define NS   2048
#define ND   4096
#define NH   32
#define NKVH 8
#define NHD  128

__device__ __forceinline__ void gl_lds16(const bf16_t* g, bf16_t* l) {
  __builtin_amdgcn_global_load_lds(
      (const __attribute__((address_space(1))) void*)g,
      (__attribute__((address_space(3))) void*)l, 16, 0, 0);
}

// ---------------- convert x fp32 -> bf16 ----------------
__global__ void convert_f32_bf16(const float* __restrict__ in, bf16_t* __restrict__ out, int n4) {
  int i = blockIdx.x * 256 + threadIdx.x;
  if (i < n4) {
    f32x4 v = *(const f32x4*)&in[(size_t)i * 4];
    bf16x4 o;
    #pragma unroll
    for (int j = 0; j < 4; ++j) o[j] = (bf16_t)v[j];
    *(bf16x4*)&out[(size_t)i * 4] = o;
  }
}

// ------------- transpose-convert W[4096][Nin] fp32 -> Wt[Nin][4096] bf16 -------------
__global__ void transpose_convert(const float* __restrict__ in, bf16_t* __restrict__ out, int Nin) {
  __shared__ float t[32][33];
  int tx = threadIdx.x & 31, ty = threadIdx.x >> 5;
  int n0 = blockIdx.x * 32, k0 = blockIdx.y * 32;
  #pragma unroll
  for (int i = 0; i < 4; ++i)
    t[ty + i * 8][tx] = in[(size_t)(k0 + ty + i * 8) * Nin + n0 + tx];
  __syncthreads();
  #pragma unroll
  for (int i = 0; i < 4; ++i)
    out[(size_t)(n0 + ty + i * 8) * 4096 + k0 + tx] = (bf16_t)t[tx][ty + i * 8];
}

// ---------------- GEMM: C[M][N] = A[M][K] * Bt[N][K]^T  (bf16 in, fp32 acc) ----------------
template <int F32OUT>
__global__ __launch_bounds__(256) void gemm_bt(const bf16_t* __restrict__ A,
                                               const bf16_t* __restrict__ Bt,
                                               void* __restrict__ Cv, int M, int N, int K) {
  __shared__ __align__(16) bf16_t As[128 * 32];
  __shared__ __align__(16) bf16_t Bs[128 * 32];
  const int tid = threadIdx.x;
  const int lane = tid & 63, wid = tid >> 6;
  const int l15 = lane & 15, l4 = lane >> 4;
  const int wr = wid >> 1, wc = wid & 1;
  const int row0 = blockIdx.x * 128, col0 = blockIdx.y * 128;

  f32x4 acc[4][4];
  #pragma unroll
  for (int m = 0; m < 4; ++m)
    #pragma unroll
    for (int n = 0; n < 4; ++n)
      #pragma unroll
      for (int j = 0; j < 4; ++j) acc[m][n][j] = 0.f;

  const bf16_t* Ab = A + (size_t)row0 * K;
  const bf16_t* Bb = Bt + (size_t)col0 * K;

  for (int k0 = 0; k0 < K; k0 += 32) {
    #pragma unroll
    for (int i = 0; i < 2; ++i) {
      int ci = i * 256 + tid;  // 512 chunks of 16B per 128x32 tile
      gl_lds16(Ab + (size_t)(ci >> 2) * K + k0 + (ci & 3) * 8, &As[ci * 8]);
      gl_lds16(Bb + (size_t)(ci >> 2) * K + k0 + (ci & 3) * 8, &Bs[ci * 8]);
    }
    __syncthreads();
    bf16x8 af[4], bfr[4];
    #pragma unroll
    for (int m = 0; m < 4; ++m)
      af[m] = *(const bf16x8*)&As[(wr * 64 + m * 16 + l15) * 32 + l4 * 8];
    #pragma unroll
    for (int n = 0; n < 4; ++n)
      bfr[n] = *(const bf16x8*)&Bs[(wc * 64 + n * 16 + l15) * 32 + l4 * 8];
    #pragma unroll
    for (int m = 0; m < 4; ++m)
      #pragma unroll
      for (int n = 0; n < 4; ++n)
        acc[m][n] = __builtin_amdgcn_mfma_f32_16x16x32_bf16(af[m], bfr[n], acc[m][n], 0, 0, 0);
    __syncthreads();
  }

  #pragma unroll
  for (int m = 0; m < 4; ++m)
    #pragma unroll
    for (int n = 0; n < 4; ++n)
      #pragma unroll
      for (int r = 0; r < 4; ++r) {
        size_t row = row0 + wr * 64 + m * 16 + l4 * 4 + r;
        size_t col = col0 + wc * 64 + n * 16 + l15;
        if (F32OUT) ((float*)Cv)[row * N + col] = acc[m][n][r];
        else ((bf16_t*)Cv)[row * N + col] = (bf16_t)acc[m][n][r];
      }
}

// ---------------- RoPE on Q and K, reshape to [b][h][s][hd] ----------------
__global__ void rope_qk(const bf16_t* __restrict__ qkv, const float* __restrict__ cosT,
                        const float* __restrict__ sinT, bf16_t* __restrict__ Q,
                        bf16_t* __restrict__ Kout) {
  int it = blockIdx.x * 256 + threadIdx.x;  // 4096 * 40 * 16
  int chunk = it & 15;
  int hs = (it >> 4) % 40;
  int m = (it >> 4) / 40;  // b*2048 + s
  int b = m >> 11, srow = m & 2047;

  bf16x8 v = *(const bf16x8*)&qkv[(size_t)m * 6144 + hs * 128 + chunk * 8];
  f32x4 c4 = *(const f32x4*)&cosT[(size_t)srow * 64 + chunk * 4];
  f32x4 s4 = *(const f32x4*)&sinT[(size_t)srow * 64 + chunk * 4];
  bf16x8 o;
  #pragma unroll
  for (int j = 0; j < 4; ++j) {
    float t1 = (float)v[2 * j], t2 = (float)v[2 * j + 1];
    o[2 * j]     = (bf16_t)(t1 * c4[j] - t2 * s4[j]);
    o[2 * j + 1] = (bf16_t)(t1 * s4[j] + t2 * c4[j]);
  }
  bf16_t* dst;
  if (hs < 32) dst = Q + (((size_t)(b * 32 + hs)) * 2048 + srow) * 128 + chunk * 8;
  else         dst = Kout + (((size_t)(b * 8 + (hs - 32))) * 2048 + srow) * 128 + chunk * 8;
  *(bf16x8*)dst = o;
}

// ---------------- transpose V section of qkv -> Vt[b*8+kv][128][2048] ----------------
__global__ void transpose_v(const bf16_t* __restrict__ qkv, bf16_t* __restrict__ Vt) {
  __shared__ bf16_t t[32][33];
  int tx = threadIdx.x & 31, ty = threadIdx.x >> 5;
  int s0 = blockIdx.x * 32, d0 = blockIdx.y * 32, g = blockIdx.z;  // g = b*8+kv
  int b = g >> 3, kv = g & 7;
  const bf16_t* src = qkv + (size_t)(b * 2048) * 6144 + 5120 + kv * 128;
  #pragma unroll
  for (int i = 0; i < 4; ++i)
    t[ty + i * 8][tx] = src[(size_t)(s0 + ty + i * 8) * 6144 + d0 + tx];
  __syncthreads();
  bf16_t* dst = Vt + (size_t)g * 128 * 2048;
  #pragma unroll
  for (int i = 0; i < 4; ++i)
    dst[(size_t)(d0 + ty + i * 8) * 2048 + s0 + tx] = t[tx][ty + i * 8];
}

// ---------------- causal flash attention, LDS-staged K/V ----------------
// Q:[b][h][2048][128], K:[b][kvh][2048][128], Vt:[b][kvh][128][2048] -> O:[m][h*128+d] bf16
// Block: 256 threads = 4 waves; Q-tile 128 rows (32/wave); KV-tile 64 keys.
// K,V tiles staged in LDS via global_load_lds with XOR swizzle (phys = logi ^ ((row&7)<<4)),
// applied on the GLOBAL SOURCE side (dest of global_load_lds must be lane-linear).
__global__ __launch_bounds__(256) void attn_kernel(const bf16_t* __restrict__ Q,
                                                   const bf16_t* __restrict__ Kc,
                                                   const bf16_t* __restrict__ Vt,
                                                   bf16_t* __restrict__ Oout) {
  __shared__ __align__(16) bf16_t Ks[64 * 128];   // [key][d], row=256B, swizzled
  __shared__ __align__(16) bf16_t Vs[128 * 64];   // [d][key], row=128B, swizzled
  __shared__ __align__(16) bf16_t Ps[4][32 * 64]; // per-wave P, [q][key], row=128B, swizzled

  const int tid = threadIdx.x, wid = tid >> 6, lane = tid & 63;
  const int l15 = lane & 15, l4 = lane >> 4;
  const int bh = blockIdx.y;
  const int b = bh >> 5, h = bh & 31, kv = h >> 2;
  const int qt = gridDim.x - 1 - blockIdx.x;  // heavy blocks dispatch first
  const int q0b = qt * 128;
  const int q0w = q0b + wid * 32;

  const bf16_t* Qp = Q + ((size_t)bh * 2048) * 128;
  const bf16_t* Kp = Kc + ((size_t)(b * 8 + kv) * 2048) * 128;
  const bf16_t* Vp = Vt + ((size_t)(b * 8 + kv) * 128) * 2048;

  // Q fragments: 32 rows x 128 k, A-frag layout (row=l15, k=l4*8)
  bf16x8 qf[2][4];
  #pragma unroll
  for (int m = 0; m < 2; ++m)
    #pragma unroll
    for (int c = 0; c < 4; ++c)
      qf[m][c] = *(const bf16x8*)&Qp[(size_t)(q0w + m * 16 + l15) * 128 + c * 32 + l4 * 8];

  f32x4 o_acc[2][8];
  #pragma unroll
  for (int m = 0; m < 2; ++m)
    #pragma unroll
    for (int nc = 0; nc < 8; ++nc)
      #pragma unroll
      for (int j = 0; j < 4; ++j) o_acc[m][nc][j] = 0.f;
  float mrow[2][4], lrow[2][4];
  #pragma unroll
  for (int m = 0; m < 2; ++m)
    #pragma unroll
    for (int r = 0; r < 4; ++r) { mrow[m][r] = -1e30f; lrow[m][r] = 0.f; }

  const float kscale = 0.08838834764831845f * 1.44269504088896f;  // 1/sqrt(128) * log2(e)
  const int nkt = (q0b + 128) / 64;

  for (int kt = 0; kt < nkt; ++kt) {
    const int k0 = kt * 64;
    // ---- stage K (64x128, 16KB) and V (128x64, 16KB) ----
    #pragma unroll
    for (int i = 0; i < 4; ++i) {
      int phys = wid * 4096 + i * 1024 + lane * 16;
      int logi = phys ^ (((phys >> 8) & 7) << 4);  // K row = 256B
      gl_lds16(Kp + (size_t)(k0 + (phys >> 8)) * 128 + ((logi & 255) >> 1), &Ks[phys >> 1]);
    }
    #pragma unroll
    for (int i = 0; i < 4; ++i) {
      int phys = wid * 4096 + i * 1024 + lane * 16;
      int logi = phys ^ (((phys >> 7) & 7) << 4);  // V row = 128B
      gl_lds16(Vp + (size_t)(phys >> 7) * 2048 + k0 + ((logi & 127) >> 1), &Vs[phys >> 1]);
    }
    __syncthreads();

    if (k0 < q0w + 32) {  // wave has at least one unmasked key in this tile
      // ---- QK^T: S[32q][64k] ----
      f32x4 s[2][4];
      #pragma unroll
      for (int m = 0; m < 2; ++m)
        #pragma unroll
        for (int n = 0; n < 4; ++n)
          #pragma unroll
          for (int j = 0; j < 4; ++j) s[m][n][j] = 0.f;
      #pragma unroll
      for (int n = 0; n < 4; ++n)
        #pragma unroll
        for (int c = 0; c < 4; ++c) {
          int lb = (n * 16 + l15) * 256 + c * 64 + l4 * 16;
          int pb = lb ^ (((lb >> 8) & 7) << 4);
          bf16x8 kf = *(const bf16x8*)&Ks[pb >> 1];
          s[0][n] = __builtin_amdgcn_mfma_f32_16x16x32_bf16(qf[0][c], kf, s[0][n], 0, 0, 0);
          s[1][n] = __builtin_amdgcn_mfma_f32_16x16x32_bf16(qf[1][c], kf, s[1][n], 0, 0, 0);
        }

      // ---- scale (exp2 domain) + causal mask (diagonal tiles only) ----
      const bool need_mask = (k0 + 63 > q0w);
      #pragma unroll
      for (int m = 0; m < 2; ++m)
        #pragma unroll
        for (int n = 0; n < 4; ++n)
          #pragma unroll
          for (int r = 0; r < 4; ++r) {
            float v = s[m][n][r] * kscale;
            if (need_mask) {
              int key = k0 + n * 16 + l15;
              int qrow = q0w + m * 16 + l4 * 4 + r;
              if (key > qrow) v = -1e30f;
            }
            s[m][n][r] = v;
          }

      // ---- online softmax ----
      float mx[2][4], sc[2][4], rs[2][4];
      #pragma unroll
      for (int m = 0; m < 2; ++m)
        #pragma unroll
        for (int r = 0; r < 4; ++r)
          mx[m][r] = fmaxf(fmaxf(s[m][0][r], s[m][1][r]), fmaxf(s[m][2][r], s[m][3][r]));
      #pragma unroll
      for (int off = 1; off < 16; off <<= 1)
        #pragma unroll
        for (int m = 0; m < 2; ++m)
          #pragma unroll
          for (int r = 0; r < 4; ++r) mx[m][r] = fmaxf(mx[m][r], __shfl_xor(mx[m][r], off));
      #pragma unroll
      for (int m = 0; m < 2; ++m)
        #pragma unroll
        for (int r = 0; r < 4; ++r) {
          float mn = fmaxf(mrow[m][r], mx[m][r]);
          sc[m][r] = exp2f(mrow[m][r] - mn);
          mrow[m][r] = mn;
          rs[m][r] = 0.f;
        }
      #pragma unroll
      for (int m = 0; m < 2; ++m)
        #pragma unroll
        for (int n = 0; n < 4; ++n)
          #pragma unroll
          for (int r = 0; r < 4; ++r) {
            float e = exp2f(s[m][n][r] - mrow[m][r]);
            s[m][n][r] = e;
            rs[m][r] += e;
          }
      #pragma unroll
      for (int off = 1; off < 16; off <<= 1)
        #pragma unroll
        for (int m = 0; m < 2; ++m)
          #pragma unroll
          for (int r = 0; r < 4; ++r) rs[m][r] += __shfl_xor(rs[m][r], off);
      #pragma unroll
      for (int m = 0; m < 2; ++m)
        #pragma unroll
        for (int r = 0; r < 4; ++r) lrow[m][r] = lrow[m][r] * sc[m][r] + rs[m][r];
      #pragma unroll
      for (int m = 0; m < 2; ++m)
        #pragma unroll
        for (int nc = 0; nc < 8; ++nc)
          #pragma unroll
          for (int r = 0; r < 4; ++r) o_acc[m][nc][r] *= sc[m][r];

      // ---- P -> per-wave LDS (bf16, swizzled) ----
      bf16_t* Pw = &Ps[wid][0];
      #pragma unroll
      for (int m = 0; m < 2; ++m)
        #pragma unroll
        for (int n = 0; n < 4; ++n)
          #pragma unroll
          for (int r = 0; r < 4; ++r) {
            int qlocal = m * 16 + l4 * 4 + r;
            int lbw = qlocal * 128 + (n * 16 + l15) * 2;
            int pbw = lbw ^ ((qlocal & 7) << 4);
            Pw[pbw >> 1] = (bf16_t)s[m][n][r];
          }

      // ---- PV: O[32q][128d] += P[32q][64k] * V[64k][128d] ----
      bf16x8 pf[2][2];
      #pragma unroll
      for (int m = 0; m < 2; ++m)
        #pragma unroll
        for (int kc = 0; kc < 2; ++kc) {
          int lb = (m * 16 + l15) * 128 + kc * 64 + l4 * 16;
          int pb = lb ^ ((((m * 16 + l15)) & 7) << 4);
          pf[m][kc] = *(const bf16x8*)&Pw[pb >> 1];
        }
      #pragma unroll
      for (int nc = 0; nc < 8; ++nc)
        #pragma unroll
        for (int kc = 0; kc < 2; ++kc) {
          int lb = (nc * 16 + l15) * 128 + kc * 64 + l4 * 16;
          int pb = lb ^ (((nc * 16 + l15) & 7) << 4);
          bf16x8 vf = *(const bf16x8*)&Vs[pb >> 1];
          o_acc[0][nc] = __builtin_amdgcn_mfma_f32_16x16x32_bf16(pf[0][kc], vf, o_acc[0][nc], 0, 0, 0);
          o_acc[1][nc] = __builtin_amdgcn_mfma_f32_16x16x32_bf16(pf[1][kc], vf, o_acc[1][nc], 0, 0, 0);
        }
    }
    __syncthreads();
  }

  float inv[2][4];
  #pragma unroll
  for (int m = 0; m < 2; ++m)
    #pragma unroll
    for (int r = 0; r < 4; ++r) inv[m][r] = 1.0f / lrow[m][r];
  bf16_t* Op = Oout + ((size_t)(b * 2048 + q0w)) * 4096 + (size_t)h * 128;
  #pragma unroll
  for (int m = 0; m < 2; ++m)
    #pragma unroll
    for (int nc = 0; nc < 8; ++nc)
      #pragma unroll
      for (int r = 0; r < 4; ++r)
        Op[(size_t)(m * 16 + l4 * 4 + r) * 4096 + nc * 16 + l15] =
            (bf16_t)(o_acc[m][nc][r] * inv[m][r]);
}

extern "C" void kernel_launch(void* const* d_in, const int* in_sizes, int n_in,
                              void* d_out, int out_size, void* d_ws, size_t ws_size,
                              hipStream_t stream) {
  const float* x    = (const float*)d_in[0];
  const float* cosT = (const float*)d_in[1];
  const float* sinT = (const float*)d_in[2];
  const float* wq   = (const float*)d_in[3];
  const float* wk   = (const float*)d_in[4];
  const float* wv   = (const float*)d_in[5];
  const float* wo   = (const float*)d_in[6];
  float* out = (float*)d_out;
  char* ws = (char*)d_ws;

  // workspace layout (151 MB), with time-sliced aliases:
  bf16_t* wqkvT = (bf16_t*)(ws + 0);           // 6144*4096*2 = 50,331,648
  bf16_t* woT   = wqkvT;                       // reused after QKV GEMM
  bf16_t* xb    = (bf16_t*)(ws + 50331648);    // 4096*4096*2 = 33,554,432
  bf16_t* Qb    = xb;                          // reused after QKV GEMM
  bf16_t* qkv   = (bf16_t*)(ws + 83886080);    // 4096*6144*2 = 50,331,648
  bf16_t* attn_out = qkv;                      // reused after rope/transpose_v
  bf16_t* Kb    = (bf16_t*)(ws + 134217728);   // 2*8*2048*128*2 = 8,388,608
  bf16_t* Vt    = (bf16_t*)(ws + 142606336);   // 8,388,608

  convert_f32_bf16<<<16384, 256, 0, stream>>>(x, xb, 4194304);
  transpose_convert<<<dim3(128, 128), 256, 0, stream>>>(wq, wqkvT, 4096);
  transpose_convert<<<dim3(32, 128), 256, 0, stream>>>(wk, wqkvT + (size_t)4096 * 4096, 1024);
  transpose_convert<<<dim3(32, 128), 256, 0, stream>>>(wv, wqkvT + (size_t)5120 * 4096, 1024);

  gemm_bt<0><<<dim3(32, 48), 256, 0, stream>>>(xb, wqkvT, qkv, 4096, 6144, 4096);

  transpose_convert<<<dim3(128, 128), 256, 0, stream>>>(wo, woT, 4096);  // wqkvT now dead
  rope_qk<<<10240, 256, 0, stream>>>(qkv, cosT, sinT, Qb, Kb);           // xb now dead
  transpose_v<<<dim3(64, 4, 16), 256, 0, stream>>>(qkv, Vt);

  attn_kernel<<<dim3(16, 64), 256, 0, stream>>>(Qb, Kb, Vt, attn_out);   // qkv now dead

  gemm_bt<1><<<dim3(32, 32), 256, 0, stream>>>(attn_out, woT, out, 4096, 4096, 4096);
}

// Round 3
// 873.821 us; speedup vs baseline: 1.7295x; 1.2897x over previous
//
#include <hip/hip_runtime.h>

typedef __bf16 bf16_t;
typedef __bf16 bf16x8 __attribute__((ext_vector_type(8)));
typedef __bf16 bf16x4 __attribute__((ext_vector_type(4)));
typedef float  f32x4  __attribute__((ext_vector_type(4)));

#define NB   2
#define NS   2048
#define ND   4096
#define NH   32
#define NKVH 8
#define NHD  128

__device__ __forceinline__ void gl_lds16(const bf16_t* g, bf16_t* l) {
  __builtin_amdgcn_global_load_lds(
      (const __attribute__((address_space(1))) void*)g,
      (__attribute__((address_space(3))) void*)l, 16, 0, 0);
}

// ---------------- convert x fp32 -> bf16 ----------------
__global__ void convert_f32_bf16(const float* __restrict__ in, bf16_t* __restrict__ out, int n4) {
  int i = blockIdx.x * 256 + threadIdx.x;
  if (i < n4) {
    f32x4 v = *(const f32x4*)&in[(size_t)i * 4];
    bf16x4 o;
    #pragma unroll
    for (int j = 0; j < 4; ++j) o[j] = (bf16_t)v[j];
    *(bf16x4*)&out[(size_t)i * 4] = o;
  }
}

// ------------- transpose-convert W[4096][Nin] fp32 -> Wt[Nin][4096] bf16 -------------
__global__ void transpose_convert(const float* __restrict__ in, bf16_t* __restrict__ out, int Nin) {
  __shared__ float t[32][33];
  int tx = threadIdx.x & 31, ty = threadIdx.x >> 5;
  int n0 = blockIdx.x * 32, k0 = blockIdx.y * 32;
  #pragma unroll
  for (int i = 0; i < 4; ++i)
    t[ty + i * 8][tx] = in[(size_t)(k0 + ty + i * 8) * Nin + n0 + tx];
  __syncthreads();
  #pragma unroll
  for (int i = 0; i < 4; ++i)
    out[(size_t)(n0 + ty + i * 8) * 4096 + k0 + tx] = (bf16_t)t[tx][ty + i * 8];
}

// ---------------- GEMM: C[M][N] = A[M][K] * Bt[N][K]^T  (bf16 in, fp32 acc) ----------------
template <int F32OUT>
__global__ __launch_bounds__(256) void gemm_bt(const bf16_t* __restrict__ A,
                                               const bf16_t* __restrict__ Bt,
                                               void* __restrict__ Cv, int M, int N, int K) {
  __shared__ __align__(16) bf16_t As[128 * 32];
  __shared__ __align__(16) bf16_t Bs[128 * 32];
  const int tid = threadIdx.x;
  const int lane = tid & 63, wid = tid >> 6;
  const int l15 = lane & 15, l4 = lane >> 4;
  const int wr = wid >> 1, wc = wid & 1;
  const int row0 = blockIdx.x * 128, col0 = blockIdx.y * 128;

  f32x4 acc[4][4];
  #pragma unroll
  for (int m = 0; m < 4; ++m)
    #pragma unroll
    for (int n = 0; n < 4; ++n)
      #pragma unroll
      for (int j = 0; j < 4; ++j) acc[m][n][j] = 0.f;

  const bf16_t* Ab = A + (size_t)row0 * K;
  const bf16_t* Bb = Bt + (size_t)col0 * K;

  for (int k0 = 0; k0 < K; k0 += 32) {
    #pragma unroll
    for (int i = 0; i < 2; ++i) {
      int ci = i * 256 + tid;  // 512 chunks of 16B per 128x32 tile
      gl_lds16(Ab + (size_t)(ci >> 2) * K + k0 + (ci & 3) * 8, &As[ci * 8]);
      gl_lds16(Bb + (size_t)(ci >> 2) * K + k0 + (ci & 3) * 8, &Bs[ci * 8]);
    }
    __syncthreads();
    bf16x8 af[4], bfr[4];
    #pragma unroll
    for (int m = 0; m < 4; ++m)
      af[m] = *(const bf16x8*)&As[(wr * 64 + m * 16 + l15) * 32 + l4 * 8];
    #pragma unroll
    for (int n = 0; n < 4; ++n)
      bfr[n] = *(const bf16x8*)&Bs[(wc * 64 + n * 16 + l15) * 32 + l4 * 8];
    #pragma unroll
    for (int m = 0; m < 4; ++m)
      #pragma unroll
      for (int n = 0; n < 4; ++n)
        acc[m][n] = __builtin_amdgcn_mfma_f32_16x16x32_bf16(af[m], bfr[n], acc[m][n], 0, 0, 0);
    __syncthreads();
  }

  #pragma unroll
  for (int m = 0; m < 4; ++m)
    #pragma unroll
    for (int n = 0; n < 4; ++n)
      #pragma unroll
      for (int r = 0; r < 4; ++r) {
        size_t row = row0 + wr * 64 + m * 16 + l4 * 4 + r;
        size_t col = col0 + wc * 64 + n * 16 + l15;
        if (F32OUT) ((float*)Cv)[row * N + col] = acc[m][n][r];
        else ((bf16_t*)Cv)[row * N + col] = (bf16_t)acc[m][n][r];
      }
}

// ---------------- RoPE on Q and K, reshape to [b][h][s][hd] ----------------
__global__ void rope_qk(const bf16_t* __restrict__ qkv, const float* __restrict__ cosT,
                        const float* __restrict__ sinT, bf16_t* __restrict__ Q,
                        bf16_t* __restrict__ Kout) {
  int it = blockIdx.x * 256 + threadIdx.x;  // 4096 * 40 * 16
  int chunk = it & 15;
  int hs = (it >> 4) % 40;
  int m = (it >> 4) / 40;  // b*2048 + s
  int b = m >> 11, srow = m & 2047;

  bf16x8 v = *(const bf16x8*)&qkv[(size_t)m * 6144 + hs * 128 + chunk * 8];
  f32x4 c4 = *(const f32x4*)&cosT[(size_t)srow * 64 + chunk * 4];
  f32x4 s4 = *(const f32x4*)&sinT[(size_t)srow * 64 + chunk * 4];
  bf16x8 o;
  #pragma unroll
  for (int j = 0; j < 4; ++j) {
    float t1 = (float)v[2 * j], t2 = (float)v[2 * j + 1];
    o[2 * j]     = (bf16_t)(t1 * c4[j] - t2 * s4[j]);
    o[2 * j + 1] = (bf16_t)(t1 * s4[j] + t2 * c4[j]);
  }
  bf16_t* dst;
  if (hs < 32) dst = Q + (((size_t)(b * 32 + hs)) * 2048 + srow) * 128 + chunk * 8;
  else         dst = Kout + (((size_t)(b * 8 + (hs - 32))) * 2048 + srow) * 128 + chunk * 8;
  *(bf16x8*)dst = o;
}

// ---------------- transpose V section of qkv -> Vt[b*8+kv][128][2048] ----------------
__global__ void transpose_v(const bf16_t* __restrict__ qkv, bf16_t* __restrict__ Vt) {
  __shared__ bf16_t t[32][33];
  int tx = threadIdx.x & 31, ty = threadIdx.x >> 5;
  int s0 = blockIdx.x * 32, d0 = blockIdx.y * 32, g = blockIdx.z;  // g = b*8+kv
  int b = g >> 3, kv = g & 7;
  const bf16_t* src = qkv + (size_t)(b * 2048) * 6144 + 5120 + kv * 128;
  #pragma unroll
  for (int i = 0; i < 4; ++i)
    t[ty + i * 8][tx] = src[(size_t)(s0 + ty + i * 8) * 6144 + d0 + tx];
  __syncthreads();
  bf16_t* dst = Vt + (size_t)g * 128 * 2048;
  #pragma unroll
  for (int i = 0; i < 4; ++i)
    dst[(size_t)(d0 + ty + i * 8) * 2048 + s0 + tx] = t[tx][ty + i * 8];
}

// ---------------- causal flash attention, paired q-tiles + double-buffered K/V ----------------
// Q:[b][h][2048][128], K:[b][kvh][2048][128], Vt:[b][kvh][128][2048] -> O:[m][h*128+d] bf16
// Block = 4 waves, 2 q-tiles of 128 rows each: {15-pair, pair} -> uniform 34 KV-tile-units/block.
// K/V double-buffered: stage(t+1) issued before compute(t), one __syncthreads per tile.
__global__ __launch_bounds__(256) void attn_kernel(const bf16_t* __restrict__ Q,
                                                   const bf16_t* __restrict__ Kc,
                                                   const bf16_t* __restrict__ Vt,
                                                   bf16_t* __restrict__ Oout) {
  __shared__ __align__(16) bf16_t Ks[2][64 * 128];   // [key][d], row=256B, swizzled
  __shared__ __align__(16) bf16_t Vs[2][128 * 64];   // [d][key], row=128B, swizzled
  __shared__ __align__(16) bf16_t Ps[4][32 * 64];    // per-wave P, [q][key], row=128B, swizzled

  const int tid = threadIdx.x, wid = tid >> 6, lane = tid & 63;
  const int l15 = lane & 15, l4 = lane >> 4;
  const int bh = blockIdx.y;
  const int b = bh >> 5, h = bh & 31, kv = h >> 2;
  const int pair = blockIdx.x;  // 0..7

  const bf16_t* Qp = Q + ((size_t)bh * 2048) * 128;
  const bf16_t* Kp = Kc + ((size_t)(b * 8 + kv) * 2048) * 128;
  const bf16_t* Vp = Vt + ((size_t)(b * 8 + kv) * 128) * 2048;

  const float kscale = 0.08838834764831845f * 1.44269504088896f;  // 1/sqrt(128) * log2(e)

  auto stage = [&](int kt, int buf) {
    const int k0 = kt * 64;
    #pragma unroll
    for (int i = 0; i < 4; ++i) {
      int phys = wid * 4096 + i * 1024 + lane * 16;
      int logi = phys ^ (((phys >> 8) & 7) << 4);  // K row = 256B
      gl_lds16(Kp + (size_t)(k0 + (phys >> 8)) * 128 + ((logi & 255) >> 1), &Ks[buf][phys >> 1]);
    }
    #pragma unroll
    for (int i = 0; i < 4; ++i) {
      int phys = wid * 4096 + i * 1024 + lane * 16;
      int logi = phys ^ (((phys >> 7) & 7) << 4);  // V row = 128B
      gl_lds16(Vp + (size_t)(phys >> 7) * 2048 + k0 + ((logi & 127) >> 1), &Vs[buf][phys >> 1]);
    }
  };

  for (int half = 0; half < 2; ++half) {
    const int qt = half ? pair : 15 - pair;
    const int q0b = qt * 128;
    const int q0w = q0b + wid * 32;
    const int nkt = (qt + 1) * 2;

    // Q fragments: 32 rows x 128 k, A-frag layout (row=l15, k=l4*8)
    bf16x8 qf[2][4];
    #pragma unroll
    for (int m = 0; m < 2; ++m)
      #pragma unroll
      for (int c = 0; c < 4; ++c)
        qf[m][c] = *(const bf16x8*)&Qp[(size_t)(q0w + m * 16 + l15) * 128 + c * 32 + l4 * 8];

    f32x4 o_acc[2][8];
    #pragma unroll
    for (int m = 0; m < 2; ++m)
      #pragma unroll
      for (int nc = 0; nc < 8; ++nc)
        #pragma unroll
        for (int j = 0; j < 4; ++j) o_acc[m][nc][j] = 0.f;
    float mrow[2][4], lrow[2][4];
    #pragma unroll
    for (int m = 0; m < 2; ++m)
      #pragma unroll
      for (int r = 0; r < 4; ++r) { mrow[m][r] = -1e30f; lrow[m][r] = 0.f; }

    stage(0, 0);
    __syncthreads();

    for (int kt = 0; kt < nkt; ++kt) {
      const int k0 = kt * 64;
      const int cur = kt & 1;
      if (kt + 1 < nkt) stage(kt + 1, cur ^ 1);  // prefetch next tile (overlapped)

      if (k0 < q0w + 32) {  // wave has at least one unmasked key in this tile
        // ---- QK^T: S[32q][64k] ----
        f32x4 s[2][4];
        #pragma unroll
        for (int m = 0; m < 2; ++m)
          #pragma unroll
          for (int n = 0; n < 4; ++n)
            #pragma unroll
            for (int j = 0; j < 4; ++j) s[m][n][j] = 0.f;
        __builtin_amdgcn_s_setprio(1);
        #pragma unroll
        for (int n = 0; n < 4; ++n)
          #pragma unroll
          for (int c = 0; c < 4; ++c) {
            int lb = (n * 16 + l15) * 256 + c * 64 + l4 * 16;
            int pb = lb ^ (((lb >> 8) & 7) << 4);
            bf16x8 kf = *(const bf16x8*)&Ks[cur][pb >> 1];
            s[0][n] = __builtin_amdgcn_mfma_f32_16x16x32_bf16(qf[0][c], kf, s[0][n], 0, 0, 0);
            s[1][n] = __builtin_amdgcn_mfma_f32_16x16x32_bf16(qf[1][c], kf, s[1][n], 0, 0, 0);
          }
        __builtin_amdgcn_s_setprio(0);

        // ---- scale (exp2 domain) + causal mask (diagonal tiles only) ----
        const bool need_mask = (k0 + 63 > q0w);
        #pragma unroll
        for (int m = 0; m < 2; ++m)
          #pragma unroll
          for (int n = 0; n < 4; ++n)
            #pragma unroll
            for (int r = 0; r < 4; ++r) {
              float v = s[m][n][r] * kscale;
              if (need_mask) {
                int key = k0 + n * 16 + l15;
                int qrow = q0w + m * 16 + l4 * 4 + r;
                if (key > qrow) v = -1e30f;
              }
              s[m][n][r] = v;
            }

        // ---- online softmax ----
        float mx[2][4], sc[2][4], rs[2][4];
        #pragma unroll
        for (int m = 0; m < 2; ++m)
          #pragma unroll
          for (int r = 0; r < 4; ++r)
            mx[m][r] = fmaxf(fmaxf(s[m][0][r], s[m][1][r]), fmaxf(s[m][2][r], s[m][3][r]));
        #pragma unroll
        for (int off = 1; off < 16; off <<= 1)
          #pragma unroll
          for (int m = 0; m < 2; ++m)
            #pragma unroll
            for (int r = 0; r < 4; ++r) mx[m][r] = fmaxf(mx[m][r], __shfl_xor(mx[m][r], off));
        #pragma unroll
        for (int m = 0; m < 2; ++m)
          #pragma unroll
          for (int r = 0; r < 4; ++r) {
            float mn = fmaxf(mrow[m][r], mx[m][r]);
            sc[m][r] = exp2f(mrow[m][r] - mn);
            mrow[m][r] = mn;
            rs[m][r] = 0.f;
          }
        #pragma unroll
        for (int m = 0; m < 2; ++m)
          #pragma unroll
          for (int n = 0; n < 4; ++n)
            #pragma unroll
            for (int r = 0; r < 4; ++r) {
              float e = exp2f(s[m][n][r] - mrow[m][r]);
              s[m][n][r] = e;
              rs[m][r] += e;
            }
        #pragma unroll
        for (int off = 1; off < 16; off <<= 1)
          #pragma unroll
          for (int m = 0; m < 2; ++m)
            #pragma unroll
            for (int r = 0; r < 4; ++r) rs[m][r] += __shfl_xor(rs[m][r], off);
        #pragma unroll
        for (int m = 0; m < 2; ++m)
          #pragma unroll
          for (int r = 0; r < 4; ++r) lrow[m][r] = lrow[m][r] * sc[m][r] + rs[m][r];
        #pragma unroll
        for (int m = 0; m < 2; ++m)
          #pragma unroll
          for (int nc = 0; nc < 8; ++nc)
            #pragma unroll
            for (int r = 0; r < 4; ++r) o_acc[m][nc][r] *= sc[m][r];

        // ---- P -> per-wave LDS (bf16, swizzled) ----
        bf16_t* Pw = &Ps[wid][0];
        #pragma unroll
        for (int m = 0; m < 2; ++m)
          #pragma unroll
          for (int n = 0; n < 4; ++n)
            #pragma unroll
            for (int r = 0; r < 4; ++r) {
              int qlocal = m * 16 + l4 * 4 + r;
              int lbw = qlocal * 128 + (n * 16 + l15) * 2;
              int pbw = lbw ^ ((qlocal & 7) << 4);
              Pw[pbw >> 1] = (bf16_t)s[m][n][r];
            }

        // ---- PV: O[32q][128d] += P[32q][64k] * V[64k][128d] ----
        bf16x8 pf[2][2];
        #pragma unroll
        for (int m = 0; m < 2; ++m)
          #pragma unroll
          for (int kc = 0; kc < 2; ++kc) {
            int lb = (m * 16 + l15) * 128 + kc * 64 + l4 * 16;
            int pb = lb ^ ((((m * 16 + l15)) & 7) << 4);
            pf[m][kc] = *(const bf16x8*)&Pw[pb >> 1];
          }
        __builtin_amdgcn_s_setprio(1);
        #pragma unroll
        for (int nc = 0; nc < 8; ++nc)
          #pragma unroll
          for (int kc = 0; kc < 2; ++kc) {
            int lb = (nc * 16 + l15) * 128 + kc * 64 + l4 * 16;
            int pb = lb ^ (((nc * 16 + l15) & 7) << 4);
            bf16x8 vf = *(const bf16x8*)&Vs[cur][pb >> 1];
            o_acc[0][nc] = __builtin_amdgcn_mfma_f32_16x16x32_bf16(pf[0][kc], vf, o_acc[0][nc], 0, 0, 0);
            o_acc[1][nc] = __builtin_amdgcn_mfma_f32_16x16x32_bf16(pf[1][kc], vf, o_acc[1][nc], 0, 0, 0);
          }
        __builtin_amdgcn_s_setprio(0);
      }
      __syncthreads();  // drains prefetch (overlapped w/ compute) + guards buffer reuse
    }

    float inv[2][4];
    #pragma unroll
    for (int m = 0; m < 2; ++m)
      #pragma unroll
      for (int r = 0; r < 4; ++r) inv[m][r] = 1.0f / lrow[m][r];
    bf16_t* Op = Oout + ((size_t)(b * 2048 + q0w)) * 4096 + (size_t)h * 128;
    #pragma unroll
    for (int m = 0; m < 2; ++m)
      #pragma unroll
      for (int nc = 0; nc < 8; ++nc)
        #pragma unroll
        for (int r = 0; r < 4; ++r)
          Op[(size_t)(m * 16 + l4 * 4 + r) * 4096 + nc * 16 + l15] =
              (bf16_t)(o_acc[m][nc][r] * inv[m][r]);
  }
}

extern "C" void kernel_launch(void* const* d_in, const int* in_sizes, int n_in,
                              void* d_out, int out_size, void* d_ws, size_t ws_size,
                              hipStream_t stream) {
  const float* x    = (const float*)d_in[0];
  const float* cosT = (const float*)d_in[1];
  const float* sinT = (const float*)d_in[2];
  const float* wq   = (const float*)d_in[3];
  const float* wk   = (const float*)d_in[4];
  const float* wv   = (const float*)d_in[5];
  const float* wo   = (const float*)d_in[6];
  float* out = (float*)d_out;
  char* ws = (char*)d_ws;

  // workspace layout (151 MB), with time-sliced aliases:
  bf16_t* wqkvT = (bf16_t*)(ws + 0);           // 6144*4096*2 = 50,331,648
  bf16_t* woT   = wqkvT;                       // reused after QKV GEMM
  bf16_t* xb    = (bf16_t*)(ws + 50331648);    // 4096*4096*2 = 33,554,432
  bf16_t* Qb    = xb;                          // reused after QKV GEMM
  bf16_t* qkv   = (bf16_t*)(ws + 83886080);    // 4096*6144*2 = 50,331,648
  bf16_t* attn_out = qkv;                      // reused after rope/transpose_v
  bf16_t* Kb    = (bf16_t*)(ws + 134217728);   // 2*8*2048*128*2 = 8,388,608
  bf16_t* Vt    = (bf16_t*)(ws + 142606336);   // 8,388,608

  convert_f32_bf16<<<16384, 256, 0, stream>>>(x, xb, 4194304);
  transpose_convert<<<dim3(128, 128), 256, 0, stream>>>(wq, wqkvT, 4096);
  transpose_convert<<<dim3(32, 128), 256, 0, stream>>>(wk, wqkvT + (size_t)4096 * 4096, 1024);
  transpose_convert<<<dim3(32, 128), 256, 0, stream>>>(wv, wqkvT + (size_t)5120 * 4096, 1024);

  gemm_bt<0><<<dim3(32, 48), 256, 0, stream>>>(xb, wqkvT, qkv, 4096, 6144, 4096);

  transpose_convert<<<dim3(128, 128), 256, 0, stream>>>(wo, woT, 4096);  // wqkvT now dead
  rope_qk<<<10240, 256, 0, stream>>>(qkv, cosT, sinT, Qb, Kb);           // xb now dead
  transpose_v<<<dim3(64, 4, 16), 256, 0, stream>>>(qkv, Vt);

  attn_kernel<<<dim3(8, 64), 256, 0, stream>>>(Qb, Kb, Vt, attn_out);    // qkv now dead

  gemm_bt<1><<<dim3(32, 32), 256, 0, stream>>>(attn_out, woT, out, 4096, 4096, 4096);
}

// Round 4
// 677.714 us; speedup vs baseline: 2.2299x; 1.2894x over previous
//
#include <hip/hip_runtime.h>

typedef __bf16 bf16_t;
typedef __bf16 bf16x8 __attribute__((ext_vector_type(8)));
typedef __bf16 bf16x4 __attribute__((ext_vector_type(4)));
typedef float  f32x4  __attribute__((ext_vector_type(4)));
typedef float  f32x16 __attribute__((ext_vector_type(16)));

#define NB   2
#define NS   2048
#define ND   4096
#define NH   32
#define NKVH 8
#define NHD  128

__device__ __forceinline__ void gl_lds16(const bf16_t* g, bf16_t* l) {
  __builtin_amdgcn_global_load_lds(
      (const __attribute__((address_space(1))) void*)g,
      (__attribute__((address_space(3))) void*)l, 16, 0, 0);
}

// ---------------- convert x fp32 -> bf16 ----------------
__global__ void convert_f32_bf16(const float* __restrict__ in, bf16_t* __restrict__ out, int n4) {
  int i = blockIdx.x * 256 + threadIdx.x;
  if (i < n4) {
    f32x4 v = *(const f32x4*)&in[(size_t)i * 4];
    bf16x4 o;
    #pragma unroll
    for (int j = 0; j < 4; ++j) o[j] = (bf16_t)v[j];
    *(bf16x4*)&out[(size_t)i * 4] = o;
  }
}

// ------------- transpose-convert W[4096][Nin] fp32 -> Wt[Nin][4096] bf16 -------------
__global__ void transpose_convert(const float* __restrict__ in, bf16_t* __restrict__ out, int Nin) {
  __shared__ float t[32][33];
  int tx = threadIdx.x & 31, ty = threadIdx.x >> 5;
  int n0 = blockIdx.x * 32, k0 = blockIdx.y * 32;
  #pragma unroll
  for (int i = 0; i < 4; ++i)
    t[ty + i * 8][tx] = in[(size_t)(k0 + ty + i * 8) * Nin + n0 + tx];
  __syncthreads();
  #pragma unroll
  for (int i = 0; i < 4; ++i)
    out[(size_t)(n0 + ty + i * 8) * 4096 + k0 + tx] = (bf16_t)t[tx][ty + i * 8];
}

// ---------------- GEMM: C[M][N] = A[M][K] * Bt[N][K]^T  (bf16 in, fp32 acc) ----------------
template <int F32OUT>
__global__ __launch_bounds__(256) void gemm_bt(const bf16_t* __restrict__ A,
                                               const bf16_t* __restrict__ Bt,
                                               void* __restrict__ Cv, int M, int N, int K) {
  __shared__ __align__(16) bf16_t As[128 * 32];
  __shared__ __align__(16) bf16_t Bs[128 * 32];
  const int tid = threadIdx.x;
  const int lane = tid & 63, wid = tid >> 6;
  const int l15 = lane & 15, l4 = lane >> 4;
  const int wr = wid >> 1, wc = wid & 1;
  const int row0 = blockIdx.x * 128, col0 = blockIdx.y * 128;

  f32x4 acc[4][4];
  #pragma unroll
  for (int m = 0; m < 4; ++m)
    #pragma unroll
    for (int n = 0; n < 4; ++n)
      #pragma unroll
      for (int j = 0; j < 4; ++j) acc[m][n][j] = 0.f;

  const bf16_t* Ab = A + (size_t)row0 * K;
  const bf16_t* Bb = Bt + (size_t)col0 * K;

  for (int k0 = 0; k0 < K; k0 += 32) {
    #pragma unroll
    for (int i = 0; i < 2; ++i) {
      int ci = i * 256 + tid;
      gl_lds16(Ab + (size_t)(ci >> 2) * K + k0 + (ci & 3) * 8, &As[ci * 8]);
      gl_lds16(Bb + (size_t)(ci >> 2) * K + k0 + (ci & 3) * 8, &Bs[ci * 8]);
    }
    __syncthreads();
    bf16x8 af[4], bfr[4];
    #pragma unroll
    for (int m = 0; m < 4; ++m)
      af[m] = *(const bf16x8*)&As[(wr * 64 + m * 16 + l15) * 32 + l4 * 8];
    #pragma unroll
    for (int n = 0; n < 4; ++n)
      bfr[n] = *(const bf16x8*)&Bs[(wc * 64 + n * 16 + l15) * 32 + l4 * 8];
    #pragma unroll
    for (int m = 0; m < 4; ++m)
      #pragma unroll
      for (int n = 0; n < 4; ++n)
        acc[m][n] = __builtin_amdgcn_mfma_f32_16x16x32_bf16(af[m], bfr[n], acc[m][n], 0, 0, 0);
    __syncthreads();
  }

  #pragma unroll
  for (int m = 0; m < 4; ++m)
    #pragma unroll
    for (int n = 0; n < 4; ++n)
      #pragma unroll
      for (int r = 0; r < 4; ++r) {
        size_t row = row0 + wr * 64 + m * 16 + l4 * 4 + r;
        size_t col = col0 + wc * 64 + n * 16 + l15;
        if (F32OUT) ((float*)Cv)[row * N + col] = acc[m][n][r];
        else ((bf16_t*)Cv)[row * N + col] = (bf16_t)acc[m][n][r];
      }
}

// ---------------- RoPE on Q and K, reshape to [b][h][s][hd] ----------------
__global__ void rope_qk(const bf16_t* __restrict__ qkv, const float* __restrict__ cosT,
                        const float* __restrict__ sinT, bf16_t* __restrict__ Q,
                        bf16_t* __restrict__ Kout) {
  int it = blockIdx.x * 256 + threadIdx.x;
  int chunk = it & 15;
  int hs = (it >> 4) % 40;
  int m = (it >> 4) / 40;
  int b = m >> 11, srow = m & 2047;

  bf16x8 v = *(const bf16x8*)&qkv[(size_t)m * 6144 + hs * 128 + chunk * 8];
  f32x4 c4 = *(const f32x4*)&cosT[(size_t)srow * 64 + chunk * 4];
  f32x4 s4 = *(const f32x4*)&sinT[(size_t)srow * 64 + chunk * 4];
  bf16x8 o;
  #pragma unroll
  for (int j = 0; j < 4; ++j) {
    float t1 = (float)v[2 * j], t2 = (float)v[2 * j + 1];
    o[2 * j]     = (bf16_t)(t1 * c4[j] - t2 * s4[j]);
    o[2 * j + 1] = (bf16_t)(t1 * s4[j] + t2 * c4[j]);
  }
  bf16_t* dst;
  if (hs < 32) dst = Q + (((size_t)(b * 32 + hs)) * 2048 + srow) * 128 + chunk * 8;
  else         dst = Kout + (((size_t)(b * 8 + (hs - 32))) * 2048 + srow) * 128 + chunk * 8;
  *(bf16x8*)dst = o;
}

// ---------------- transpose V section of qkv -> Vt[b*8+kv][128][2048] ----------------
__global__ void transpose_v(const bf16_t* __restrict__ qkv, bf16_t* __restrict__ Vt) {
  __shared__ bf16_t t[32][33];
  int tx = threadIdx.x & 31, ty = threadIdx.x >> 5;
  int s0 = blockIdx.x * 32, d0 = blockIdx.y * 32, g = blockIdx.z;
  int b = g >> 3, kv = g & 7;
  const bf16_t* src = qkv + (size_t)(b * 2048) * 6144 + 5120 + kv * 128;
  #pragma unroll
  for (int i = 0; i < 4; ++i)
    t[ty + i * 8][tx] = src[(size_t)(s0 + ty + i * 8) * 6144 + d0 + tx];
  __syncthreads();
  bf16_t* dst = Vt + (size_t)g * 128 * 2048;
  #pragma unroll
  for (int i = 0; i < 4; ++i)
    dst[(size_t)(d0 + ty + i * 8) * 2048 + s0 + tx] = t[tx][ty + i * 8];
}

// ---------------- causal flash attention, 8-wave swapped-QK in-register softmax ----------------
// Q:[b][h][2048][128], K:[b][kvh][2048][128], Vt:[b][kvh][128][2048] -> O:[m][h*128+d] bf16
// Block = 8 waves (512 thr), 256 q-rows (32/wave), KVBLK=64, K/V dbuf LDS.
// QK^T computed SWAPPED: s = mfma_32x32x16(A=K, B=Q) -> each lane holds 32 P-values
// of ONE q-row (q = lane&31); key(reg,hi) = kb*32 + (r&3)+8*(r>>2)+4*hi. Softmax in-lane.
__global__ __launch_bounds__(512, 2) void attn_kernel(const bf16_t* __restrict__ Q,
                                                      const bf16_t* __restrict__ Kc,
                                                      const bf16_t* __restrict__ Vt,
                                                      bf16_t* __restrict__ Oout) {
  __shared__ __align__(16) bf16_t Ks[2][64 * 128];   // [key][d] 256B rows, 4-bit XOR swizzle
  __shared__ __align__(16) bf16_t Vs[2][128 * 64];   // [d][key] 128B rows, 3-bit XOR swizzle

  const int tid = threadIdx.x, wid = tid >> 6, lane = tid & 63;
  const int l31 = lane & 31, hi = lane >> 5;
  const int bh = blockIdx.y;
  const int b = bh >> 5, h = bh & 31, kv = h >> 2;
  const int pr = blockIdx.x;  // 0..3 ; q-tile pair {7-pr, pr} -> uniform 36 KV-tiles/block

  const bf16_t* Qp = Q + ((size_t)bh * 2048) * 128;
  const bf16_t* Kp = Kc + ((size_t)(b * 8 + kv) * 2048) * 128;
  const bf16_t* Vp = Vt + ((size_t)(b * 8 + kv) * 128) * 2048;

  const float kscale = 0.08838834764831845f * 1.44269504088896f;  // 1/sqrt(128) * log2(e)
  // SIMD-balanced wave->q-offset map: SIMD s hosts waves {s, s+4} with offsets {o, 224-o}
  const int qoff = (wid < 4) ? wid * 32 : 224 - (wid - 4) * 32;

  auto stage = [&](int kt, int buf) {
    const int k0 = kt * 64;
    #pragma unroll
    for (int i = 0; i < 2; ++i) {
      int phys = i * 8192 + tid * 16;
      int logi = phys ^ (((phys >> 8) & 15) << 4);
      gl_lds16(Kp + (size_t)(k0 + (phys >> 8)) * 128 + ((logi & 255) >> 1), &Ks[buf][phys >> 1]);
    }
    #pragma unroll
    for (int i = 0; i < 2; ++i) {
      int phys = i * 8192 + tid * 16;
      int logi = phys ^ (((phys >> 7) & 7) << 4);
      gl_lds16(Vp + (size_t)(phys >> 7) * 2048 + k0 + ((logi & 127) >> 1), &Vs[buf][phys >> 1]);
    }
  };

  for (int half = 0; half < 2; ++half) {
    const int qt = half ? pr : 7 - pr;
    const int q0b = qt * 256;
    const int q0w = q0b + qoff;
    const int qg = q0w + l31;      // this lane's q-row
    const int nkt = (qt + 1) * 4;

    // Q fragments (B-operand): q = lane&31, k = c*16 + hi*8 + j ; pre-scaled by kscale
    bf16x8 qf[8];
    #pragma unroll
    for (int c = 0; c < 8; ++c) {
      bf16x8 t = *(const bf16x8*)&Qp[(size_t)qg * 128 + c * 16 + hi * 8];
      #pragma unroll
      for (int j = 0; j < 8; ++j) t[j] = (bf16_t)((float)t[j] * kscale);
      qf[c] = t;
    }

    f32x16 oa[4];
    #pragma unroll
    for (int nc = 0; nc < 4; ++nc)
      #pragma unroll
      for (int r = 0; r < 16; ++r) oa[nc][r] = 0.f;
    float m_old = -1e30f, lrow = 0.f;

    stage(0, 0);
    __syncthreads();

    for (int kt = 0; kt < nkt; ++kt) {
      const int k0 = kt * 64, cur = kt & 1;
      if (kt + 1 < nkt) stage(kt + 1, cur ^ 1);  // prefetch overlapped with compute

      if (k0 <= q0w + 31) {
        // ---- QK^T swapped: s[kb] = K[kb*32..][.] x Q -> P^T (col=q) ----
        f32x16 s0, s1;
        #pragma unroll
        for (int r = 0; r < 16; ++r) { s0[r] = 0.f; s1[r] = 0.f; }
        __builtin_amdgcn_s_setprio(1);
        #pragma unroll
        for (int c = 0; c < 8; ++c) {
          int lb0 = l31 * 256 + c * 32 + hi * 16;
          int pb0 = lb0 ^ (((lb0 >> 8) & 15) << 4);
          bf16x8 kf0 = *(const bf16x8*)&Ks[cur][pb0 >> 1];
          s0 = __builtin_amdgcn_mfma_f32_32x32x16_bf16(kf0, qf[c], s0, 0, 0, 0);
          int lb1 = (32 + l31) * 256 + c * 32 + hi * 16;
          int pb1 = lb1 ^ (((lb1 >> 8) & 15) << 4);
          bf16x8 kf1 = *(const bf16x8*)&Ks[cur][pb1 >> 1];
          s1 = __builtin_amdgcn_mfma_f32_32x32x16_bf16(kf1, qf[c], s1, 0, 0, 0);
        }
        __builtin_amdgcn_s_setprio(0);

        // ---- causal mask (diagonal tiles only); Q pre-scaled so s is in exp2 domain ----
        if (k0 + 63 > q0w) {
          #pragma unroll
          for (int r = 0; r < 16; ++r) {
            int key0 = k0 + ((r & 3) + 8 * (r >> 2)) + 4 * hi;
            if (key0 > qg) s0[r] = -1e30f;
            if (key0 + 32 > qg) s1[r] = -1e30f;
          }
        }

        // ---- in-lane row max (q = l31 for all 32 values) ----
        float m8[8];
        #pragma unroll
        for (int j = 0; j < 8; ++j)
          m8[j] = fmaxf(fmaxf(s0[j], s0[j + 8]), fmaxf(s1[j], s1[j + 8]));
        float ma = fmaxf(fmaxf(m8[0], m8[4]), fmaxf(m8[1], m8[5]));
        float mb = fmaxf(fmaxf(m8[2], m8[6]), fmaxf(m8[3], m8[7]));
        float mh = fmaxf(ma, mb);
        float mfull = fmaxf(mh, __shfl_xor(mh, 32));
        float mn = fmaxf(m_old, mfull);
        bool nores = (mfull <= m_old);
        float sc = exp2f(m_old - mn);
        float mprev = m_old;
        m_old = mn;

        // ---- O rescale (skip when no row max grew in this wave) ----
        if (!__all((int)nores)) {
          #pragma unroll
          for (int r = 0; r < 16; ++r) {
            int qi = (r & 3) + 8 * (r >> 2) + 4 * hi;
            float scv = __int_as_float(__builtin_amdgcn_ds_bpermute(qi << 2, __float_as_int(sc)));
            oa[0][r] *= scv; oa[1][r] *= scv; oa[2][r] *= scv; oa[3][r] *= scv;
          }
        }
        (void)mprev;

        // ---- exp + row sum ----
        #pragma unroll
        for (int r = 0; r < 16; ++r) {
          s0[r] = exp2f(s0[r] - mn);
          s1[r] = exp2f(s1[r] - mn);
        }
        float rsA = 0.f, rsB = 0.f, rsC = 0.f, rsD = 0.f;
        #pragma unroll
        for (int r = 0; r < 16; r += 4) {
          rsA += s0[r];     rsB += s0[r + 1]; rsC += s0[r + 2]; rsD += s0[r + 3];
          rsA += s1[r];     rsB += s1[r + 1]; rsC += s1[r + 2]; rsD += s1[r + 3];
        }
        float rs = (rsA + rsB) + (rsC + rsD);
        rs += __shfl_xor(rs, 32);
        lrow = lrow * sc + rs;

        // ---- PV: per k-slot ks (16 keys), assemble P A-frag in regs via half-exchange ----
        #pragma unroll
        for (int ks = 0; ks < 4; ++ks) {
          const int qi0 = (ks & 1) * 8;
          // keep-quad: regs qi0 + hi*4 .. +3 ; send-quad: regs qi0 + (1-hi)*4 .. +3
          union { bf16_t hh[4]; int ii[2]; } ku, su;
          #pragma unroll
          for (int j = 0; j < 4; ++j) {
            float lo, hv;
            if (ks >> 1) { lo = s1[qi0 + j]; hv = s1[qi0 + 4 + j]; }
            else         { lo = s0[qi0 + j]; hv = s0[qi0 + 4 + j]; }
            ku.hh[j] = (bf16_t)(hi ? hv : lo);
            su.hh[j] = (bf16_t)(hi ? lo : hv);
          }
          int r0 = __shfl_xor(su.ii[0], 32), r1 = __shfl_xor(su.ii[1], 32);
          union { int ii[4]; bf16x8 v; } fa;
          fa.ii[0] = hi ? r0 : ku.ii[0];
          fa.ii[1] = hi ? r1 : ku.ii[1];
          fa.ii[2] = hi ? ku.ii[0] : r0;
          fa.ii[3] = hi ? ku.ii[1] : r1;
          __builtin_amdgcn_s_setprio(1);
          #pragma unroll
          for (int nc = 0; nc < 4; ++nc) {
            int lb = (nc * 32 + l31) * 128 + ks * 32 + hi * 16;
            int pb = lb ^ (((lb >> 7) & 7) << 4);
            bf16x8 vf = *(const bf16x8*)&Vs[cur][pb >> 1];
            oa[nc] = __builtin_amdgcn_mfma_f32_32x32x16_bf16(fa.v, vf, oa[nc], 0, 0, 0);
          }
          __builtin_amdgcn_s_setprio(0);
        }
      }
      __syncthreads();  // buffer reuse guard + drains prefetch
    }

    // ---- epilogue: O[q][d] ; q = (r&3)+8*(r>>2)+4*hi (in regs), d = nc*32+l31 ----
    float inv = 1.0f / lrow;
    bf16_t* Op = Oout + ((size_t)(b * 2048 + q0w)) * 4096 + (size_t)h * 128;
    #pragma unroll
    for (int r = 0; r < 16; ++r) {
      int qi = (r & 3) + 8 * (r >> 2) + 4 * hi;
      float iv = __int_as_float(__builtin_amdgcn_ds_bpermute(qi << 2, __float_as_int(inv)));
      #pragma unroll
      for (int nc = 0; nc < 4; ++nc)
        Op[(size_t)qi * 4096 + nc * 32 + l31] = (bf16_t)(oa[nc][r] * iv);
    }
  }
}

extern "C" void kernel_launch(void* const* d_in, const int* in_sizes, int n_in,
                              void* d_out, int out_size, void* d_ws, size_t ws_size,
                              hipStream_t stream) {
  const float* x    = (const float*)d_in[0];
  const float* cosT = (const float*)d_in[1];
  const float* sinT = (const float*)d_in[2];
  const float* wq   = (const float*)d_in[3];
  const float* wk   = (const float*)d_in[4];
  const float* wv   = (const float*)d_in[5];
  const float* wo   = (const float*)d_in[6];
  float* out = (float*)d_out;
  char* ws = (char*)d_ws;

  bf16_t* wqkvT = (bf16_t*)(ws + 0);           // 6144*4096*2
  bf16_t* woT   = wqkvT;                       // reused after QKV GEMM
  bf16_t* xb    = (bf16_t*)(ws + 50331648);    // 4096*4096*2
  bf16_t* Qb    = xb;                          // reused after QKV GEMM
  bf16_t* qkv   = (bf16_t*)(ws + 83886080);    // 4096*6144*2
  bf16_t* attn_out = qkv;                      // reused after rope/transpose_v
  bf16_t* Kb    = (bf16_t*)(ws + 134217728);   // 2*8*2048*128*2
  bf16_t* Vt    = (bf16_t*)(ws + 142606336);   // 2*8*128*2048*2

  convert_f32_bf16<<<16384, 256, 0, stream>>>(x, xb, 4194304);
  transpose_convert<<<dim3(128, 128), 256, 0, stream>>>(wq, wqkvT, 4096);
  transpose_convert<<<dim3(32, 128), 256, 0, stream>>>(wk, wqkvT + (size_t)4096 * 4096, 1024);
  transpose_convert<<<dim3(32, 128), 256, 0, stream>>>(wv, wqkvT + (size_t)5120 * 4096, 1024);

  gemm_bt<0><<<dim3(32, 48), 256, 0, stream>>>(xb, wqkvT, qkv, 4096, 6144, 4096);

  transpose_convert<<<dim3(128, 128), 256, 0, stream>>>(wo, woT, 4096);  // wqkvT now dead
  rope_qk<<<10240, 256, 0, stream>>>(qkv, cosT, sinT, Qb, Kb);           // xb now dead
  transpose_v<<<dim3(64, 4, 16), 256, 0, stream>>>(qkv, Vt);

  attn_kernel<<<dim3(4, 64), 512, 0, stream>>>(Qb, Kb, Vt, attn_out);    // qkv now dead

  gemm_bt<1><<<dim3(32, 32), 256, 0, stream>>>(attn_out, woT, out, 4096, 4096, 4096);
}

// Round 5
// 598.060 us; speedup vs baseline: 2.5269x; 1.1332x over previous
//
#include <hip/hip_runtime.h>

typedef __bf16 bf16_t;
typedef __bf16 bf16x8 __attribute__((ext_vector_type(8)));
typedef __bf16 bf16x4 __attribute__((ext_vector_type(4)));
typedef float  f32x4  __attribute__((ext_vector_type(4)));
typedef float  f32x16 __attribute__((ext_vector_type(16)));

#define NB   2
#define NS   2048
#define ND   4096
#define NH   32
#define NKVH 8
#define NHD  128

#define BAR()    asm volatile("s_barrier" ::: "memory")
#define LGKM0()  asm volatile("s_waitcnt lgkmcnt(0)" ::: "memory")
#define VMCNT8() asm volatile("s_waitcnt vmcnt(8)" ::: "memory")
#define VMCNT0() asm volatile("s_waitcnt vmcnt(0)" ::: "memory")

__device__ __forceinline__ void gl_lds16(const bf16_t* g, bf16_t* l) {
  __builtin_amdgcn_global_load_lds(
      (const __attribute__((address_space(1))) void*)g,
      (__attribute__((address_space(3))) void*)l, 16, 0, 0);
}

// ---------------- convert x fp32 -> bf16 ----------------
__global__ void convert_f32_bf16(const float* __restrict__ in, bf16_t* __restrict__ out, int n4) {
  int i = blockIdx.x * 256 + threadIdx.x;
  if (i < n4) {
    f32x4 v = *(const f32x4*)&in[(size_t)i * 4];
    bf16x4 o;
    #pragma unroll
    for (int j = 0; j < 4; ++j) o[j] = (bf16_t)v[j];
    *(bf16x4*)&out[(size_t)i * 4] = o;
  }
}

// ------------- transpose-convert W[4096][Nin] fp32 -> Wt[Nin][4096] bf16 -------------
__global__ void transpose_convert(const float* __restrict__ in, bf16_t* __restrict__ out, int Nin) {
  __shared__ float t[32][33];
  int tx = threadIdx.x & 31, ty = threadIdx.x >> 5;
  int n0 = blockIdx.x * 32, k0 = blockIdx.y * 32;
  #pragma unroll
  for (int i = 0; i < 4; ++i)
    t[ty + i * 8][tx] = in[(size_t)(k0 + ty + i * 8) * Nin + n0 + tx];
  __syncthreads();
  #pragma unroll
  for (int i = 0; i < 4; ++i)
    out[(size_t)(n0 + ty + i * 8) * 4096 + k0 + tx] = (bf16_t)t[tx][ty + i * 8];
}

// ============ 256x256 8-phase GEMM: C[M][N] = A[M][K] * Bt[N][K]^T (bf16 in, fp32 acc) ============
// 512 thr = 8 waves (2M x 4N), BK=64, 32x32x16 MFMA, wave tile 128x64.
// LDS: 2 x (A 32KB + B 32KB) = 128KB; tile t+2 overwrites buf[t&1] mid-iteration after
// explicit lgkmcnt(0)+barrier read-drain. Counted vmcnt(8) once per K-tile (T4); LDS rows
// (128B) XOR-swizzled byte^=((row&7)<<4) on both stage-source and ds_read (T2).
template <int F32OUT>
__global__ __launch_bounds__(512, 2) void gemm256(const bf16_t* __restrict__ A,
                                                  const bf16_t* __restrict__ Bt,
                                                  void* __restrict__ Cv, int M, int N, int K) {
  __shared__ __align__(16) bf16_t As[2][256 * 64];
  __shared__ __align__(16) bf16_t Bs[2][256 * 64];
  const int tid = threadIdx.x, lane = tid & 63, wid = tid >> 6;
  const int l31 = lane & 31, hi = lane >> 5;
  const int wm = wid >> 2, wn = wid & 3;

  // T1: bijective XCD swizzle (nwg % 8 == 0 for both call sites)
  const int gx = gridDim.x;
  const int nwg = gx * gridDim.y;
  const int id = blockIdx.y * gx + blockIdx.x;
  const int wg = (id & 7) * (nwg >> 3) + (id >> 3);
  const int bx = wg % gx, by = wg / gx;
  const int row0 = bx * 256, col0 = by * 256;

  const bf16_t* Ab = A + (size_t)row0 * K;
  const bf16_t* Bb = Bt + (size_t)col0 * K;

  auto stageA = [&](int t2, int buf) {
    const int k0 = t2 * 64;
    #pragma unroll
    for (int i = 0; i < 4; ++i) {
      int phys = i * 8192 + tid * 16;
      int logi = phys ^ (((phys >> 7) & 7) << 4);
      gl_lds16(Ab + (size_t)(logi >> 7) * K + k0 + ((logi & 127) >> 1), &As[buf][phys >> 1]);
    }
  };
  auto stageB = [&](int t2, int buf) {
    const int k0 = t2 * 64;
    #pragma unroll
    for (int i = 0; i < 4; ++i) {
      int phys = i * 8192 + tid * 16;
      int logi = phys ^ (((phys >> 7) & 7) << 4);
      gl_lds16(Bb + (size_t)(logi >> 7) * K + k0 + ((logi & 127) >> 1), &Bs[buf][phys >> 1]);
    }
  };

  f32x16 acc[4][2];
  #pragma unroll
  for (int m = 0; m < 4; ++m)
    #pragma unroll
    for (int n = 0; n < 2; ++n)
      #pragma unroll
      for (int r = 0; r < 16; ++r) acc[m][n][r] = 0.f;

  const int nt = K >> 6;
  // prologue: tiles 0,1 in flight; drain tile 0 (vmcnt(8) leaves tile 1's 8 loads flying)
  stageB(0, 0); stageA(0, 0);
  stageB(1, 1); stageA(1, 1);
  VMCNT8();
  BAR();

  const int arow = wm * 128 + l31;  // + m*32
  const int brow = wn * 64 + l31;   // + n*32
  const int rsw = (l31 & 7) << 4;   // row&7 == l31&7 for all frag rows

  for (int t = 0; t < nt; ++t) {
    const int cur = t & 1;
    const bool pf = (t < nt - 2);
    bf16x8 a01[2][4], a23[2][4], b0[4], b1[4];

    // ---- P1: read A[m0,1] + B[n0]; MFMA m01 x n0 ----
    #pragma unroll
    for (int m = 0; m < 2; ++m)
      #pragma unroll
      for (int kk = 0; kk < 4; ++kk) {
        int lb = (arow + m * 32) * 128 + kk * 32 + hi * 16;
        a01[m][kk] = *(const bf16x8*)&As[cur][(lb ^ rsw) >> 1];
      }
    #pragma unroll
    for (int kk = 0; kk < 4; ++kk) {
      int lb = brow * 128 + kk * 32 + hi * 16;
      b0[kk] = *(const bf16x8*)&Bs[cur][(lb ^ rsw) >> 1];
    }
    BAR();
    __builtin_amdgcn_s_setprio(1);
    #pragma unroll
    for (int kk = 0; kk < 4; ++kk) {
      acc[0][0] = __builtin_amdgcn_mfma_f32_32x32x16_bf16(a01[0][kk], b0[kk], acc[0][0], 0, 0, 0);
      acc[1][0] = __builtin_amdgcn_mfma_f32_32x32x16_bf16(a01[1][kk], b0[kk], acc[1][0], 0, 0, 0);
    }
    __builtin_amdgcn_s_setprio(0);
    BAR();

    // ---- P2: read B[n1]; MFMA m01 x n1; drain all LDS reads (B fully read) ----
    #pragma unroll
    for (int kk = 0; kk < 4; ++kk) {
      int lb = (brow + 32) * 128 + kk * 32 + hi * 16;
      b1[kk] = *(const bf16x8*)&Bs[cur][(lb ^ rsw) >> 1];
    }
    BAR();
    __builtin_amdgcn_s_setprio(1);
    #pragma unroll
    for (int kk = 0; kk < 4; ++kk) {
      acc[0][1] = __builtin_amdgcn_mfma_f32_32x32x16_bf16(a01[0][kk], b1[kk], acc[0][1], 0, 0, 0);
      acc[1][1] = __builtin_amdgcn_mfma_f32_32x32x16_bf16(a01[1][kk], b1[kk], acc[1][1], 0, 0, 0);
    }
    __builtin_amdgcn_s_setprio(0);
    LGKM0();  // every wave's B-reads in regs before anyone stages B(t+2) into Bs[cur]
    BAR();

    // ---- P3: stage B(t+2)->Bs[cur]; read A[m2,3]; MFMA m23 x n0; drain A-reads ----
    if (pf) stageB(t + 2, cur);
    #pragma unroll
    for (int m = 0; m < 2; ++m)
      #pragma unroll
      for (int kk = 0; kk < 4; ++kk) {
        int lb = (arow + 64 + m * 32) * 128 + kk * 32 + hi * 16;
        a23[m][kk] = *(const bf16x8*)&As[cur][(lb ^ rsw) >> 1];
      }
    BAR();
    __builtin_amdgcn_s_setprio(1);
    #pragma unroll
    for (int kk = 0; kk < 4; ++kk) {
      acc[2][0] = __builtin_amdgcn_mfma_f32_32x32x16_bf16(a23[0][kk], b0[kk], acc[2][0], 0, 0, 0);
      acc[3][0] = __builtin_amdgcn_mfma_f32_32x32x16_bf16(a23[1][kk], b0[kk], acc[3][0], 0, 0, 0);
    }
    __builtin_amdgcn_s_setprio(0);
    LGKM0();  // A-reads in regs before anyone stages A(t+2) into As[cur]
    BAR();

    // ---- P4: stage A(t+2)->As[cur]; MFMA m23 x n1 (regs only); counted vmcnt ----
    if (pf) stageA(t + 2, cur);
    BAR();
    __builtin_amdgcn_s_setprio(1);
    #pragma unroll
    for (int kk = 0; kk < 4; ++kk) {
      acc[2][1] = __builtin_amdgcn_mfma_f32_32x32x16_bf16(a23[0][kk], b1[kk], acc[2][1], 0, 0, 0);
      acc[3][1] = __builtin_amdgcn_mfma_f32_32x32x16_bf16(a23[1][kk], b1[kk], acc[3][1], 0, 0, 0);
    }
    __builtin_amdgcn_s_setprio(0);
    if (pf) { VMCNT8(); } else { VMCNT0(); }  // oldest 8 = tile t+1 landed; t+2 stays in flight
    BAR();
  }

  // epilogue: C[row][col]; row_local = (r&3)+8*(r>>2)+4*hi, col = l31 (verified 32x32 layout)
  #pragma unroll
  for (int m = 0; m < 4; ++m)
    #pragma unroll
    for (int n = 0; n < 2; ++n)
      #pragma unroll
      for (int r = 0; r < 16; ++r) {
        int rl = (r & 3) + 8 * (r >> 2) + 4 * hi;
        size_t row = (size_t)row0 + wm * 128 + m * 32 + rl;
        size_t col = (size_t)col0 + wn * 64 + n * 32 + l31;
        if (F32OUT) ((float*)Cv)[row * N + col] = acc[m][n][r];
        else ((bf16_t*)Cv)[row * N + col] = (bf16_t)acc[m][n][r];
      }
}

// ---------------- RoPE on Q and K, reshape to [b][h][s][hd] ----------------
__global__ void rope_qk(const bf16_t* __restrict__ qkv, const float* __restrict__ cosT,
                        const float* __restrict__ sinT, bf16_t* __restrict__ Q,
                        bf16_t* __restrict__ Kout) {
  int it = blockIdx.x * 256 + threadIdx.x;
  int chunk = it & 15;
  int hs = (it >> 4) % 40;
  int m = (it >> 4) / 40;
  int b = m >> 11, srow = m & 2047;

  bf16x8 v = *(const bf16x8*)&qkv[(size_t)m * 6144 + hs * 128 + chunk * 8];
  f32x4 c4 = *(const f32x4*)&cosT[(size_t)srow * 64 + chunk * 4];
  f32x4 s4 = *(const f32x4*)&sinT[(size_t)srow * 64 + chunk * 4];
  bf16x8 o;
  #pragma unroll
  for (int j = 0; j < 4; ++j) {
    float t1 = (float)v[2 * j], t2 = (float)v[2 * j + 1];
    o[2 * j]     = (bf16_t)(t1 * c4[j] - t2 * s4[j]);
    o[2 * j + 1] = (bf16_t)(t1 * s4[j] + t2 * c4[j]);
  }
  bf16_t* dst;
  if (hs < 32) dst = Q + (((size_t)(b * 32 + hs)) * 2048 + srow) * 128 + chunk * 8;
  else         dst = Kout + (((size_t)(b * 8 + (hs - 32))) * 2048 + srow) * 128 + chunk * 8;
  *(bf16x8*)dst = o;
}

// ---------------- transpose V section of qkv -> Vt[b*8+kv][128][2048] ----------------
__global__ void transpose_v(const bf16_t* __restrict__ qkv, bf16_t* __restrict__ Vt) {
  __shared__ bf16_t t[32][33];
  int tx = threadIdx.x & 31, ty = threadIdx.x >> 5;
  int s0 = blockIdx.x * 32, d0 = blockIdx.y * 32, g = blockIdx.z;
  int b = g >> 3, kv = g & 7;
  const bf16_t* src = qkv + (size_t)(b * 2048) * 6144 + 5120 + kv * 128;
  #pragma unroll
  for (int i = 0; i < 4; ++i)
    t[ty + i * 8][tx] = src[(size_t)(s0 + ty + i * 8) * 6144 + d0 + tx];
  __syncthreads();
  bf16_t* dst = Vt + (size_t)g * 128 * 2048;
  #pragma unroll
  for (int i = 0; i < 4; ++i)
    dst[(size_t)(d0 + ty + i * 8) * 2048 + s0 + tx] = t[tx][ty + i * 8];
}

// ---------------- causal flash attention, 8-wave swapped-QK in-register softmax ----------------
__global__ __launch_bounds__(512, 2) void attn_kernel(const bf16_t* __restrict__ Q,
                                                      const bf16_t* __restrict__ Kc,
                                                      const bf16_t* __restrict__ Vt,
                                                      bf16_t* __restrict__ Oout) {
  __shared__ __align__(16) bf16_t Ks[2][64 * 128];   // [key][d] 256B rows, 4-bit XOR swizzle
  __shared__ __align__(16) bf16_t Vs[2][128 * 64];   // [d][key] 128B rows, 3-bit XOR swizzle

  const int tid = threadIdx.x, wid = tid >> 6, lane = tid & 63;
  const int l31 = lane & 31, hi = lane >> 5;
  const int bh = blockIdx.y;
  const int b = bh >> 5, h = bh & 31, kv = h >> 2;
  const int pr = blockIdx.x;  // 0..3 ; q-tile pair {7-pr, pr} -> uniform 36 KV-tiles/block

  const bf16_t* Qp = Q + ((size_t)bh * 2048) * 128;
  const bf16_t* Kp = Kc + ((size_t)(b * 8 + kv) * 2048) * 128;
  const bf16_t* Vp = Vt + ((size_t)(b * 8 + kv) * 128) * 2048;

  const float kscale = 0.08838834764831845f * 1.44269504088896f;  // 1/sqrt(128) * log2(e)
  const int qoff = (wid < 4) ? wid * 32 : 224 - (wid - 4) * 32;

  auto stage = [&](int kt, int buf) {
    const int k0 = kt * 64;
    #pragma unroll
    for (int i = 0; i < 2; ++i) {
      int phys = i * 8192 + tid * 16;
      int logi = phys ^ (((phys >> 8) & 15) << 4);
      gl_lds16(Kp + (size_t)(k0 + (phys >> 8)) * 128 + ((logi & 255) >> 1), &Ks[buf][phys >> 1]);
    }
    #pragma unroll
    for (int i = 0; i < 2; ++i) {
      int phys = i * 8192 + tid * 16;
      int logi = phys ^ (((phys >> 7) & 7) << 4);
      gl_lds16(Vp + (size_t)(phys >> 7) * 2048 + k0 + ((logi & 127) >> 1), &Vs[buf][phys >> 1]);
    }
  };

  for (int half = 0; half < 2; ++half) {
    const int qt = half ? pr : 7 - pr;
    const int q0b = qt * 256;
    const int q0w = q0b + qoff;
    const int qg = q0w + l31;
    const int nkt = (qt + 1) * 4;

    bf16x8 qf[8];
    #pragma unroll
    for (int c = 0; c < 8; ++c) {
      bf16x8 t = *(const bf16x8*)&Qp[(size_t)qg * 128 + c * 16 + hi * 8];
      #pragma unroll
      for (int j = 0; j < 8; ++j) t[j] = (bf16_t)((float)t[j] * kscale);
      qf[c] = t;
    }

    f32x16 oa[4];
    #pragma unroll
    for (int nc = 0; nc < 4; ++nc)
      #pragma unroll
      for (int r = 0; r < 16; ++r) oa[nc][r] = 0.f;
    float m_old = -1e30f, lrow = 0.f;

    stage(0, 0);
    __syncthreads();

    for (int kt = 0; kt < nkt; ++kt) {
      const int k0 = kt * 64, cur = kt & 1;
      if (kt + 1 < nkt) stage(kt + 1, cur ^ 1);

      if (k0 <= q0w + 31) {
        f32x16 s0, s1;
        #pragma unroll
        for (int r = 0; r < 16; ++r) { s0[r] = 0.f; s1[r] = 0.f; }
        __builtin_amdgcn_s_setprio(1);
        #pragma unroll
        for (int c = 0; c < 8; ++c) {
          int lb0 = l31 * 256 + c * 32 + hi * 16;
          int pb0 = lb0 ^ (((lb0 >> 8) & 15) << 4);
          bf16x8 kf0 = *(const bf16x8*)&Ks[cur][pb0 >> 1];
          s0 = __builtin_amdgcn_mfma_f32_32x32x16_bf16(kf0, qf[c], s0, 0, 0, 0);
          int lb1 = (32 + l31) * 256 + c * 32 + hi * 16;
          int pb1 = lb1 ^ (((lb1 >> 8) & 15) << 4);
          bf16x8 kf1 = *(const bf16x8*)&Ks[cur][pb1 >> 1];
          s1 = __builtin_amdgcn_mfma_f32_32x32x16_bf16(kf1, qf[c], s1, 0, 0, 0);
        }
        __builtin_amdgcn_s_setprio(0);

        if (k0 + 63 > q0w) {
          #pragma unroll
          for (int r = 0; r < 16; ++r) {
            int key0 = k0 + ((r & 3) + 8 * (r >> 2)) + 4 * hi;
            if (key0 > qg) s0[r] = -1e30f;
            if (key0 + 32 > qg) s1[r] = -1e30f;
          }
        }

        float m8[8];
        #pragma unroll
        for (int j = 0; j < 8; ++j)
          m8[j] = fmaxf(fmaxf(s0[j], s0[j + 8]), fmaxf(s1[j], s1[j + 8]));
        float ma = fmaxf(fmaxf(m8[0], m8[4]), fmaxf(m8[1], m8[5]));
        float mb = fmaxf(fmaxf(m8[2], m8[6]), fmaxf(m8[3], m8[7]));
        float mh = fmaxf(ma, mb);
        float mfull = fmaxf(mh, __shfl_xor(mh, 32));
        float mn = fmaxf(m_old, mfull);
        bool nores = (mfull <= m_old);
        float sc = exp2f(m_old - mn);
        m_old = mn;

        if (!__all((int)nores)) {
          #pragma unroll
          for (int r = 0; r < 16; ++r) {
            int qi = (r & 3) + 8 * (r >> 2) + 4 * hi;
            float scv = __int_as_float(__builtin_amdgcn_ds_bpermute(qi << 2, __float_as_int(sc)));
            oa[0][r] *= scv; oa[1][r] *= scv; oa[2][r] *= scv; oa[3][r] *= scv;
          }
        }

        #pragma unroll
        for (int r = 0; r < 16; ++r) {
          s0[r] = exp2f(s0[r] - mn);
          s1[r] = exp2f(s1[r] - mn);
        }
        float rsA = 0.f, rsB = 0.f, rsC = 0.f, rsD = 0.f;
        #pragma unroll
        for (int r = 0; r < 16; r += 4) {
          rsA += s0[r];     rsB += s0[r + 1]; rsC += s0[r + 2]; rsD += s0[r + 3];
          rsA += s1[r];     rsB += s1[r + 1]; rsC += s1[r + 2]; rsD += s1[r + 3];
        }
        float rs = (rsA + rsB) + (rsC + rsD);
        rs += __shfl_xor(rs, 32);
        lrow = lrow * sc + rs;

        #pragma unroll
        for (int ks = 0; ks < 4; ++ks) {
          const int qi0 = (ks & 1) * 8;
          union { bf16_t hh[4]; int ii[2]; } ku, su;
          #pragma unroll
          for (int j = 0; j < 4; ++j) {
            float lo, hv;
            if (ks >> 1) { lo = s1[qi0 + j]; hv = s1[qi0 + 4 + j]; }
            else         { lo = s0[qi0 + j]; hv = s0[qi0 + 4 + j]; }
            ku.hh[j] = (bf16_t)(hi ? hv : lo);
            su.hh[j] = (bf16_t)(hi ? lo : hv);
          }
          int r0 = __shfl_xor(su.ii[0], 32), r1 = __shfl_xor(su.ii[1], 32);
          union { int ii[4]; bf16x8 v; } fa;
          fa.ii[0] = hi ? r0 : ku.ii[0];
          fa.ii[1] = hi ? r1 : ku.ii[1];
          fa.ii[2] = hi ? ku.ii[0] : r0;
          fa.ii[3] = hi ? ku.ii[1] : r1;
          __builtin_amdgcn_s_setprio(1);
          #pragma unroll
          for (int nc = 0; nc < 4; ++nc) {
            int lb = (nc * 32 + l31) * 128 + ks * 32 + hi * 16;
            int pb = lb ^ (((lb >> 7) & 7) << 4);
            bf16x8 vf = *(const bf16x8*)&Vs[cur][pb >> 1];
            oa[nc] = __builtin_amdgcn_mfma_f32_32x32x16_bf16(fa.v, vf, oa[nc], 0, 0, 0);
          }
          __builtin_amdgcn_s_setprio(0);
        }
      }
      __syncthreads();
    }

    float inv = 1.0f / lrow;
    bf16_t* Op = Oout + ((size_t)(b * 2048 + q0w)) * 4096 + (size_t)h * 128;
    #pragma unroll
    for (int r = 0; r < 16; ++r) {
      int qi = (r & 3) + 8 * (r >> 2) + 4 * hi;
      float iv = __int_as_float(__builtin_amdgcn_ds_bpermute(qi << 2, __float_as_int(inv)));
      #pragma unroll
      for (int nc = 0; nc < 4; ++nc)
        Op[(size_t)qi * 4096 + nc * 32 + l31] = (bf16_t)(oa[nc][r] * iv);
    }
  }
}

extern "C" void kernel_launch(void* const* d_in, const int* in_sizes, int n_in,
                              void* d_out, int out_size, void* d_ws, size_t ws_size,
                              hipStream_t stream) {
  const float* x    = (const float*)d_in[0];
  const float* cosT = (const float*)d_in[1];
  const float* sinT = (const float*)d_in[2];
  const float* wq   = (const float*)d_in[3];
  const float* wk   = (const float*)d_in[4];
  const float* wv   = (const float*)d_in[5];
  const float* wo   = (const float*)d_in[6];
  float* out = (float*)d_out;
  char* ws = (char*)d_ws;

  bf16_t* wqkvT = (bf16_t*)(ws + 0);           // 6144*4096*2
  bf16_t* woT   = wqkvT;                       // reused after QKV GEMM
  bf16_t* xb    = (bf16_t*)(ws + 50331648);    // 4096*4096*2
  bf16_t* Qb    = xb;                          // reused after QKV GEMM
  bf16_t* qkv   = (bf16_t*)(ws + 83886080);    // 4096*6144*2
  bf16_t* attn_out = qkv;                      // reused after rope/transpose_v
  bf16_t* Kb    = (bf16_t*)(ws + 134217728);
  bf16_t* Vt    = (bf16_t*)(ws + 142606336);

  convert_f32_bf16<<<16384, 256, 0, stream>>>(x, xb, 4194304);
  transpose_convert<<<dim3(128, 128), 256, 0, stream>>>(wq, wqkvT, 4096);
  transpose_convert<<<dim3(32, 128), 256, 0, stream>>>(wk, wqkvT + (size_t)4096 * 4096, 1024);
  transpose_convert<<<dim3(32, 128), 256, 0, stream>>>(wv, wqkvT + (size_t)5120 * 4096, 1024);

  gemm256<0><<<dim3(16, 24), 512, 0, stream>>>(xb, wqkvT, qkv, 4096, 6144, 4096);

  transpose_convert<<<dim3(128, 128), 256, 0, stream>>>(wo, woT, 4096);  // wqkvT now dead
  rope_qk<<<10240, 256, 0, stream>>>(qkv, cosT, sinT, Qb, Kb);           // xb now dead
  transpose_v<<<dim3(64, 4, 16), 256, 0, stream>>>(qkv, Vt);

  attn_kernel<<<dim3(4, 64), 512, 0, stream>>>(Qb, Kb, Vt, attn_out);    // qkv now dead

  gemm256<1><<<dim3(16, 16), 512, 0, stream>>>(attn_out, woT, out, 4096, 4096, 4096);
}